// Round 1
// baseline (432.479 us; speedup 1.0000x reference)
//
#include <hip/hip_runtime.h>

typedef unsigned short u16;
typedef __bf16 bf16x8 __attribute__((ext_vector_type(8)));
typedef float f32x4 __attribute__((ext_vector_type(4)));

#define SEQ   2048
#define DDIM  1024
#define EDIM  2048
#define FDIM  4224   /* 2E + S_ATT */
#define SATT  128
#define NBATCH 4

__device__ __forceinline__ u16 f2bf(float f) {
  unsigned u = __float_as_uint(f);
  unsigned r = (u + 0x7fffu + ((u >> 16) & 1u)) >> 16;
  return (u16)r;
}
__device__ __forceinline__ float bf2f(u16 v) {
  return __uint_as_float(((unsigned)v) << 16);
}

// global -> LDS direct (16B per lane). LDS ptr must be wave-uniform base;
// HW adds lane*16. AS casts via integer reinterpret (CK-style, low 32 bits
// of a generic LDS pointer are the LDS offset on gfx9+).
__device__ __forceinline__ void gload16(const u16* g, u16* l) {
  auto gp = (const __attribute__((address_space(1))) u16*)(unsigned long long)g;
  auto lp = (__attribute__((address_space(3))) u16*)(unsigned)(unsigned long long)l;
  __builtin_amdgcn_global_load_lds(gp, lp, 16, 0, 0);
}

// ---------------- elementwise / small kernels ----------------

__global__ void cvt_bf16_kernel(const float* __restrict__ in, u16* __restrict__ out, int n4) {
  int i = blockIdx.x * blockDim.x + threadIdx.x;
  if (i >= n4) return;
  float4 v = reinterpret_cast<const float4*>(in)[i];
  unsigned p0 = (unsigned)f2bf(v.x) | ((unsigned)f2bf(v.y) << 16);
  unsigned p1 = (unsigned)f2bf(v.z) | ((unsigned)f2bf(v.w) << 16);
  uint2 pk; pk.x = p0; pk.y = p1;
  reinterpret_cast<uint2*>(out)[i] = pk;
}

// one block (256 thr) per row of D=1024
__global__ void rms_kernel(const float* __restrict__ x, const float* __restrict__ ln_g,
                           u16* __restrict__ xn) {
  int row = blockIdx.x;
  int t = threadIdx.x;
  const float4* xr = reinterpret_cast<const float4*>(x + (size_t)row * DDIM);
  float4 v = xr[t];
  float s = v.x * v.x + v.y * v.y + v.z * v.z + v.w * v.w;
#pragma unroll
  for (int off = 32; off > 0; off >>= 1) s += __shfl_down(s, off);
  __shared__ float wsum[4];
  int lane = t & 63, wv = t >> 6;
  if (lane == 0) wsum[wv] = s;
  __syncthreads();
  float tot = wsum[0] + wsum[1] + wsum[2] + wsum[3];
  float rms = sqrtf(tot * (1.0f / (float)DDIM));
  float scale = ln_g[0] / fmaxf(rms, 1e-5f);
  unsigned p0 = (unsigned)f2bf(v.x * scale) | ((unsigned)f2bf(v.y * scale) << 16);
  unsigned p1 = (unsigned)f2bf(v.z * scale) | ((unsigned)f2bf(v.w * scale) << 16);
  uint2 pk; pk.x = p0; pk.y = p1;
  reinterpret_cast<uint2*>(xn + (size_t)row * DDIM)[t] = pk;
}

// q/k from base cols of uv: one block (128 thr) per row
__global__ void qk_kernel(const u16* __restrict__ uv, const float* __restrict__ pos_enc,
                          const float* __restrict__ gamma, const float* __restrict__ beta,
                          u16* __restrict__ q, u16* __restrict__ k) {
  int r = blockIdx.x;
  int t = threadIdx.x;
  int s = r & (SEQ - 1);
  float bval = bf2f(uv[(size_t)r * FDIM + 2 * EDIM + t]);
  float pe = pos_enc[(size_t)s * SATT + t];
  float qv = bval * gamma[t] + beta[t] + pe;
  float kv = bval * gamma[SATT + t] + beta[SATT + t] + pe;
  q[(size_t)r * SATT + t] = f2bf(qv);
  k[(size_t)r * SATT + t] = f2bf(kv);
}

// vt[e][s] = uv[s][E + e]   (32x32 tiles, block 32x8)
__global__ void transpose_v(const u16* __restrict__ uv, u16* __restrict__ vt) {
  __shared__ u16 tile[32][33];
  int e0 = blockIdx.x * 32, s0 = blockIdx.y * 32;
  int tx = threadIdx.x, ty = threadIdx.y;
#pragma unroll
  for (int j = 0; j < 32; j += 8)
    tile[ty + j][tx] = uv[(size_t)(s0 + ty + j) * FDIM + EDIM + e0 + tx];
  __syncthreads();
#pragma unroll
  for (int j = 0; j < 32; j += 8)
    vt[(size_t)(e0 + ty + j) * SEQ + s0 + tx] = tile[tx][ty + j];
}

// ---------------- MFMA GEMM: C(M,N) = A(M,K) * B(N,K)^T ----------------
// 128x128 tile, BK=32, 4 waves in 2x2, each wave 64x64 via 4x4 frags of 16x16x32.
// EPI: 0 = silu -> bf16
//      1 = relu(v/sqrt(128))^2 -> bf16
//      2 = v * U[m][n] -> bf16
//      3 = Xres[m][n]*rscale[n] + v -> f32
template <int EPI>
__global__ __launch_bounds__(256) void gemm_bt(
    const u16* __restrict__ A, const u16* __restrict__ B,
    int M, int N, int K,
    u16* __restrict__ Cbf, float* __restrict__ Cf,
    const u16* __restrict__ U, int ldu,
    const float* __restrict__ Xres, const float* __restrict__ rscale) {
  __shared__ u16 As[128 * 32];
  __shared__ u16 Bs[128 * 32];
  const int tid = threadIdx.x;
  const int wave = tid >> 6, lane = tid & 63;
  const int wr = wave >> 1, wc = wave & 1;
  const int bm = blockIdx.y, bn = blockIdx.x;
  const size_t abase = (size_t)bm * 128 * K;
  const size_t bbase = (size_t)bn * 128 * K;
  const int srow = tid >> 2;         // 0..63
  const int scol = (tid & 3) * 8;    // 0,8,16,24

  f32x4 acc[4][4];
#pragma unroll
  for (int i = 0; i < 4; i++)
#pragma unroll
    for (int j = 0; j < 4; j++) acc[i][j] = f32x4{0.f, 0.f, 0.f, 0.f};

  const int fr = lane & 15;
  const int fk = (lane >> 4) * 8;

  for (int k0 = 0; k0 < K; k0 += 32) {
#pragma unroll
    for (int r = 0; r < 2; r++) {
      const u16* gA = A + abase + (size_t)(r * 64 + srow) * K + k0 + scol;
      const u16* gB = B + bbase + (size_t)(r * 64 + srow) * K + k0 + scol;
      gload16(gA, As + r * 2048 + wave * 512);
      gload16(gB, Bs + r * 2048 + wave * 512);
    }
    __syncthreads();
    bf16x8 af[4], bfr[4];
#pragma unroll
    for (int i = 0; i < 4; i++) {
      af[i]  = *reinterpret_cast<const bf16x8*>(&As[(wr * 64 + i * 16 + fr) * 32 + fk]);
      bfr[i] = *reinterpret_cast<const bf16x8*>(&Bs[(wc * 64 + i * 16 + fr) * 32 + fk]);
    }
#pragma unroll
    for (int i = 0; i < 4; i++)
#pragma unroll
      for (int j = 0; j < 4; j++)
        acc[i][j] = __builtin_amdgcn_mfma_f32_16x16x32_bf16(af[i], bfr[j], acc[i][j], 0, 0, 0);
    __syncthreads();
  }

  const int m0 = bm * 128 + wr * 64;
  const int n0 = bn * 128 + wc * 64;
  const int rsub = (lane >> 4) * 4;
  const int ccol = lane & 15;
#pragma unroll
  for (int i = 0; i < 4; i++) {
#pragma unroll
    for (int j = 0; j < 4; j++) {
      int n = n0 + j * 16 + ccol;
#pragma unroll
      for (int t = 0; t < 4; t++) {
        int m = m0 + i * 16 + rsub + t;
        float v = acc[i][j][t];
        size_t idx = (size_t)m * N + n;
        if constexpr (EPI == 0) {
          float sv = v / (1.f + __expf(-v));
          Cbf[idx] = f2bf(sv);
        } else if constexpr (EPI == 1) {
          float sc = v * 0.08838834764831845f;  // 1/sqrt(128)
          sc = sc > 0.f ? sc * sc : 0.f;
          Cbf[idx] = f2bf(sc);
        } else if constexpr (EPI == 2) {
          float uvl = bf2f(U[(size_t)m * ldu + n]);
          Cbf[idx] = f2bf(v * uvl);
        } else {
          Cf[idx] = Xres[idx] * rscale[n] + v;
        }
      }
    }
  }
}

// ---------------- launcher ----------------

extern "C" void kernel_launch(void* const* d_in, const int* in_sizes, int n_in,
                              void* d_out, int out_size, void* d_ws, size_t ws_size,
                              hipStream_t stream) {
  const float* x        = (const float*)d_in[0];
  const float* pos_enc  = (const float*)d_in[1];
  const float* uv_w     = (const float*)d_in[2];
  const float* o_w      = (const float*)d_in[3];
  const float* gamma    = (const float*)d_in[4];
  const float* beta     = (const float*)d_in[5];
  const float* ln_g     = (const float*)d_in[6];
  const float* res_scale= (const float*)d_in[7];
  float* out = (float*)d_out;

  char* p = (char*)d_ws;
  auto alloc = [&](size_t bytes) {
    char* r = p;
    p += (bytes + 255) & ~(size_t)255;
    return r;
  };
  u16* uvw_bf = (u16*)alloc((size_t)FDIM * DDIM * 2);
  u16* ow_bf  = (u16*)alloc((size_t)DDIM * EDIM * 2);
  u16* z      = (u16*)alloc((size_t)NBATCH * SEQ * EDIM * 2);
  u16* vt     = (u16*)alloc((size_t)EDIM * SEQ * 2);
  u16* pmat   = (u16*)alloc((size_t)SEQ * SEQ * 2);
  size_t fixed = (size_t)(p - (char*)d_ws);
  const size_t perbc = (size_t)SEQ * DDIM * 2 + (size_t)SEQ * FDIM * 2 +
                       2 * (size_t)SEQ * SATT * 2 + 4 * 256;
  int BC = (ws_size >= fixed + 4 * perbc) ? 4 : 1;
  u16* xn = (u16*)alloc((size_t)BC * SEQ * DDIM * 2);
  u16* uv = (u16*)alloc((size_t)BC * SEQ * FDIM * 2);
  u16* qb = (u16*)alloc((size_t)BC * SEQ * SATT * 2);
  u16* kb = (u16*)alloc((size_t)BC * SEQ * SATT * 2);

  {
    int n4 = FDIM * DDIM / 4;
    cvt_bf16_kernel<<<(n4 + 255) / 256, 256, 0, stream>>>(uv_w, uvw_bf, n4);
    n4 = DDIM * EDIM / 4;
    cvt_bf16_kernel<<<(n4 + 255) / 256, 256, 0, stream>>>(o_w, ow_bf, n4);
  }

  for (int b0 = 0; b0 < NBATCH; b0 += BC) {
    int rows = BC * SEQ;
    rms_kernel<<<rows, 256, 0, stream>>>(x + (size_t)b0 * SEQ * DDIM, ln_g, xn);
    gemm_bt<0><<<dim3(FDIM / 128, rows / 128), 256, 0, stream>>>(
        xn, uvw_bf, rows, FDIM, DDIM, uv, nullptr, nullptr, 0, nullptr, nullptr);
    qk_kernel<<<rows, SATT, 0, stream>>>(uv, pos_enc, gamma, beta, qb, kb);
    for (int bb = 0; bb < BC; bb++) {
      int b = b0 + bb;
      const u16* uvb = uv + (size_t)bb * SEQ * FDIM;
      transpose_v<<<dim3(EDIM / 32, SEQ / 32), dim3(32, 8), 0, stream>>>(uvb, vt);
      gemm_bt<1><<<dim3(SEQ / 128, SEQ / 128), 256, 0, stream>>>(
          qb + (size_t)bb * SEQ * SATT, kb + (size_t)bb * SEQ * SATT,
          SEQ, SEQ, SATT, pmat, nullptr, nullptr, 0, nullptr, nullptr);
      gemm_bt<2><<<dim3(EDIM / 128, SEQ / 128), 256, 0, stream>>>(
          pmat, vt, SEQ, EDIM, SEQ, z + (size_t)b * SEQ * EDIM, nullptr,
          uvb, FDIM, nullptr, nullptr);
    }
  }
  gemm_bt<3><<<dim3(DDIM / 128, (NBATCH * SEQ) / 128), 256, 0, stream>>>(
      z, ow_bf, NBATCH * SEQ, DDIM, EDIM, nullptr, out, nullptr, 0,
      x, res_scale);
}

// Round 2
// 354.259 us; speedup vs baseline: 1.2208x; 1.2208x over previous
//
#include <hip/hip_runtime.h>

typedef unsigned short u16;
typedef __bf16 bf16x8 __attribute__((ext_vector_type(8)));
typedef float f32x4 __attribute__((ext_vector_type(4)));

#define SEQ   2048
#define DDIM  1024
#define EDIM  2048
#define FDIM  4224   /* 2E + S_ATT */
#define SATT  128
#define NBATCH 4

__device__ __forceinline__ u16 f2bf(float f) {
  unsigned u = __float_as_uint(f);
  unsigned r = (u + 0x7fffu + ((u >> 16) & 1u)) >> 16;
  return (u16)r;
}
__device__ __forceinline__ float bf2f(u16 v) {
  return __uint_as_float(((unsigned)v) << 16);
}

// global -> LDS direct (16B per lane). LDS dest is wave-uniform base + lane*16.
__device__ __forceinline__ void gload16(const u16* g, u16* l) {
  auto gp = (const __attribute__((address_space(1))) u16*)(unsigned long long)g;
  auto lp = (__attribute__((address_space(3))) u16*)(unsigned)(unsigned long long)l;
  __builtin_amdgcn_global_load_lds(gp, lp, 16, 0, 0);
}

// ---------------- elementwise / small kernels ----------------

__global__ void cvt_bf16_kernel(const float* __restrict__ in, u16* __restrict__ out, int n4) {
  int i = blockIdx.x * blockDim.x + threadIdx.x;
  if (i >= n4) return;
  float4 v = reinterpret_cast<const float4*>(in)[i];
  unsigned p0 = (unsigned)f2bf(v.x) | ((unsigned)f2bf(v.y) << 16);
  unsigned p1 = (unsigned)f2bf(v.z) | ((unsigned)f2bf(v.w) << 16);
  uint2 pk; pk.x = p0; pk.y = p1;
  reinterpret_cast<uint2*>(out)[i] = pk;
}

// one block (256 thr) per row of D=1024
__global__ void rms_kernel(const float* __restrict__ x, const float* __restrict__ ln_g,
                           u16* __restrict__ xn) {
  int row = blockIdx.x;
  int t = threadIdx.x;
  const float4* xr = reinterpret_cast<const float4*>(x + (size_t)row * DDIM);
  float4 v = xr[t];
  float s = v.x * v.x + v.y * v.y + v.z * v.z + v.w * v.w;
#pragma unroll
  for (int off = 32; off > 0; off >>= 1) s += __shfl_down(s, off);
  __shared__ float wsum[4];
  int lane = t & 63, wv = t >> 6;
  if (lane == 0) wsum[wv] = s;
  __syncthreads();
  float tot = wsum[0] + wsum[1] + wsum[2] + wsum[3];
  float rms = sqrtf(tot * (1.0f / (float)DDIM));
  float scale = ln_g[0] / fmaxf(rms, 1e-5f);
  unsigned p0 = (unsigned)f2bf(v.x * scale) | ((unsigned)f2bf(v.y * scale) << 16);
  unsigned p1 = (unsigned)f2bf(v.z * scale) | ((unsigned)f2bf(v.w * scale) << 16);
  uint2 pk; pk.x = p0; pk.y = p1;
  reinterpret_cast<uint2*>(xn + (size_t)row * DDIM)[t] = pk;
}

// q/k from base cols of uv: one block (128 thr) per row
__global__ void qk_kernel(const u16* __restrict__ uv, const float* __restrict__ pos_enc,
                          const float* __restrict__ gamma, const float* __restrict__ beta,
                          u16* __restrict__ q, u16* __restrict__ k) {
  int r = blockIdx.x;
  int t = threadIdx.x;
  int s = r & (SEQ - 1);
  float bval = bf2f(uv[(size_t)r * FDIM + 2 * EDIM + t]);
  float pe = pos_enc[(size_t)s * SATT + t];
  float qv = bval * gamma[t] + beta[t] + pe;
  float kv = bval * gamma[SATT + t] + beta[SATT + t] + pe;
  q[(size_t)r * SATT + t] = f2bf(qv);
  k[(size_t)r * SATT + t] = f2bf(kv);
}

// vt[b][e][s] = uv[b][s][E + e]   (32x32 tiles, block 32x8, grid.z = batch)
__global__ void transpose_v(const u16* __restrict__ uv, u16* __restrict__ vt) {
  __shared__ u16 tile[32][33];
  int b = blockIdx.z;
  uv += (size_t)b * SEQ * FDIM;
  vt += (size_t)b * EDIM * SEQ;
  int e0 = blockIdx.x * 32, s0 = blockIdx.y * 32;
  int tx = threadIdx.x, ty = threadIdx.y;
#pragma unroll
  for (int j = 0; j < 32; j += 8)
    tile[ty + j][tx] = uv[(size_t)(s0 + ty + j) * FDIM + EDIM + e0 + tx];
  __syncthreads();
#pragma unroll
  for (int j = 0; j < 32; j += 8)
    vt[(size_t)(e0 + ty + j) * SEQ + s0 + tx] = tile[tx][ty + j];
}

// ---------------- MFMA GEMM: C(M,N) = A(M,K) * B(N,K)^T ----------------
// 128x128 tile, BK=32, 4 waves 2x2, each wave 64x64 via 4x4 frags of 16x16x32.
// grid.z = batch (strides sA/sB/sC/sU elements); XCD-swizzled block mapping.
// EPI: 0 = silu -> bf16
//      1 = relu(v/sqrt(128))^2 -> bf16
//      2 = v * U[m][n] -> bf16
//      3 = Xres[m][n]*rscale[n] + v -> f32
template <int EPI>
__global__ __launch_bounds__(256) void gemm_bt(
    const u16* __restrict__ A, const u16* __restrict__ B,
    int M, int N, int K,
    u16* __restrict__ Cbf, float* __restrict__ Cf,
    const u16* __restrict__ U, int ldu,
    const float* __restrict__ Xres, const float* __restrict__ rscale,
    size_t sA, size_t sB, size_t sC, size_t sU) {
  __shared__ u16 As[128 * 32];
  __shared__ u16 Bs[128 * 32];
  const int tid = threadIdx.x;
  const int wave = tid >> 6, lane = tid & 63;
  const int wr = wave >> 1, wc = wave & 1;

  // batch offsets
  const int bz = blockIdx.z;
  A += (size_t)bz * sA;
  B += (size_t)bz * sB;
  U += (size_t)bz * sU;

  // XCD-aware bijective swizzle within the z-slice (nwg % 8 == 0 for all shapes)
  const int nbx = gridDim.x;
  int l = blockIdx.y * nbx + blockIdx.x;
  const int cpx = (nbx * gridDim.y) >> 3;
  l = (l & 7) * cpx + (l >> 3);
  const int bn = l % nbx;
  const int bm = l / nbx;

  const size_t abase = (size_t)bm * 128 * K;
  const size_t bbase = (size_t)bn * 128 * K;
  const int srow = tid >> 2;         // 0..63
  const int scol = (tid & 3) * 8;    // 0,8,16,24

  f32x4 acc[4][4];
#pragma unroll
  for (int i = 0; i < 4; i++)
#pragma unroll
    for (int j = 0; j < 4; j++) acc[i][j] = f32x4{0.f, 0.f, 0.f, 0.f};

  const int fr = lane & 15;
  const int fk = (lane >> 4) * 8;

  for (int k0 = 0; k0 < K; k0 += 32) {
#pragma unroll
    for (int r = 0; r < 2; r++) {
      const u16* gA = A + abase + (size_t)(r * 64 + srow) * K + k0 + scol;
      const u16* gB = B + bbase + (size_t)(r * 64 + srow) * K + k0 + scol;
      gload16(gA, As + r * 2048 + wave * 512);
      gload16(gB, Bs + r * 2048 + wave * 512);
    }
    __syncthreads();
    bf16x8 af[4], bfr[4];
#pragma unroll
    for (int i = 0; i < 4; i++) {
      af[i]  = *reinterpret_cast<const bf16x8*>(&As[(wr * 64 + i * 16 + fr) * 32 + fk]);
      bfr[i] = *reinterpret_cast<const bf16x8*>(&Bs[(wc * 64 + i * 16 + fr) * 32 + fk]);
    }
#pragma unroll
    for (int i = 0; i < 4; i++)
#pragma unroll
      for (int j = 0; j < 4; j++)
        acc[i][j] = __builtin_amdgcn_mfma_f32_16x16x32_bf16(af[i], bfr[j], acc[i][j], 0, 0, 0);
    __syncthreads();
  }

  const int m0 = bm * 128 + wr * 64;
  const int n0 = bn * 128 + wc * 64;
  const int rsub = (lane >> 4) * 4;
  const int ccol = lane & 15;
#pragma unroll
  for (int i = 0; i < 4; i++) {
#pragma unroll
    for (int j = 0; j < 4; j++) {
      int n = n0 + j * 16 + ccol;
#pragma unroll
      for (int t = 0; t < 4; t++) {
        int m = m0 + i * 16 + rsub + t;
        float v = acc[i][j][t];
        size_t idx = (size_t)m * N + n;
        if constexpr (EPI == 0) {
          float sv = v / (1.f + __expf(-v));
          Cbf[(size_t)bz * sC + idx] = f2bf(sv);
        } else if constexpr (EPI == 1) {
          float sc = v * 0.08838834764831845f;  // 1/sqrt(128)
          sc = sc > 0.f ? sc * sc : 0.f;
          Cbf[(size_t)bz * sC + idx] = f2bf(sc);
        } else if constexpr (EPI == 2) {
          float uvl = bf2f(U[(size_t)m * ldu + n]);
          Cbf[(size_t)bz * sC + idx] = f2bf(v * uvl);
        } else {
          Cf[idx] = Xres[idx] * rscale[n] + v;
        }
      }
    }
  }
}

// ---------------- launcher ----------------

extern "C" void kernel_launch(void* const* d_in, const int* in_sizes, int n_in,
                              void* d_out, int out_size, void* d_ws, size_t ws_size,
                              hipStream_t stream) {
  const float* x        = (const float*)d_in[0];
  const float* pos_enc  = (const float*)d_in[1];
  const float* uv_w     = (const float*)d_in[2];
  const float* o_w      = (const float*)d_in[3];
  const float* gamma    = (const float*)d_in[4];
  const float* beta     = (const float*)d_in[5];
  const float* ln_g     = (const float*)d_in[6];
  const float* res_scale= (const float*)d_in[7];
  float* out = (float*)d_out;

  const size_t SZ_UVW  = (size_t)FDIM * DDIM * 2;
  const size_t SZ_OW   = (size_t)DDIM * EDIM * 2;
  const size_t SZ_Z    = (size_t)NBATCH * SEQ * EDIM * 2;
  const size_t SZ_XN   = (size_t)NBATCH * SEQ * DDIM * 2;
  const size_t SZ_UV   = (size_t)NBATCH * SEQ * FDIM * 2;
  const size_t SZ_QK   = (size_t)NBATCH * SEQ * SATT * 2;
  const size_t SZ_VT1  = (size_t)EDIM * SEQ * 2;
  const size_t SZ_P1   = (size_t)SEQ * SEQ * 2;
  auto al = [](size_t b) { return (b + 255) & ~(size_t)255; };
  const size_t need_full =
      al(SZ_UVW) + al(SZ_OW) + al(SZ_Z) + al(SZ_XN) + al(SZ_UV) + 2 * al(SZ_QK) +
      (size_t)NBATCH * (al(SZ_VT1) + al(SZ_P1));
  const bool FULL = ws_size >= need_full;

  char* p = (char*)d_ws;
  auto alloc = [&](size_t bytes) {
    char* r = p;
    p += (bytes + 255) & ~(size_t)255;
    return r;
  };
  u16* uvw_bf = (u16*)alloc(SZ_UVW);
  u16* ow_bf  = (u16*)alloc(SZ_OW);
  u16* z      = (u16*)alloc(SZ_Z);
  u16* vt     = (u16*)alloc(FULL ? (size_t)NBATCH * al(SZ_VT1) : SZ_VT1);
  u16* pmat   = (u16*)alloc(FULL ? (size_t)NBATCH * al(SZ_P1) : SZ_P1);
  size_t fixed = (size_t)(p - (char*)d_ws);
  const size_t perbc = (size_t)SEQ * DDIM * 2 + (size_t)SEQ * FDIM * 2 +
                       2 * (size_t)SEQ * SATT * 2 + 4 * 256;
  int BC = FULL ? NBATCH : ((ws_size >= fixed + 4 * perbc) ? 4 : 1);
  u16* xn = (u16*)alloc((size_t)BC * SEQ * DDIM * 2);
  u16* uv = (u16*)alloc((size_t)BC * SEQ * FDIM * 2);
  u16* qb = (u16*)alloc((size_t)BC * SEQ * SATT * 2);
  u16* kb = (u16*)alloc((size_t)BC * SEQ * SATT * 2);

  const size_t sVT = (al(SZ_VT1) >> 1);   // u16 elements per batch slice
  const size_t sP  = (al(SZ_P1) >> 1);

  {
    int n4 = FDIM * DDIM / 4;
    cvt_bf16_kernel<<<(n4 + 255) / 256, 256, 0, stream>>>(uv_w, uvw_bf, n4);
    n4 = DDIM * EDIM / 4;
    cvt_bf16_kernel<<<(n4 + 255) / 256, 256, 0, stream>>>(o_w, ow_bf, n4);
  }

  for (int b0 = 0; b0 < NBATCH; b0 += BC) {
    int rows = BC * SEQ;
    rms_kernel<<<rows, 256, 0, stream>>>(x + (size_t)b0 * SEQ * DDIM, ln_g, xn);
    gemm_bt<0><<<dim3(FDIM / 128, rows / 128), 256, 0, stream>>>(
        xn, uvw_bf, rows, FDIM, DDIM, uv, nullptr, nullptr, 0, nullptr, nullptr,
        0, 0, 0, 0);
    qk_kernel<<<rows, SATT, 0, stream>>>(uv, pos_enc, gamma, beta, qb, kb);

    if (FULL) {
      transpose_v<<<dim3(EDIM / 32, SEQ / 32, NBATCH), dim3(32, 8), 0, stream>>>(uv, vt);
      gemm_bt<1><<<dim3(SEQ / 128, SEQ / 128, NBATCH), 256, 0, stream>>>(
          qb, kb, SEQ, SEQ, SATT, pmat, nullptr, nullptr, 0, nullptr, nullptr,
          (size_t)SEQ * SATT, (size_t)SEQ * SATT, sP, 0);
      gemm_bt<2><<<dim3(EDIM / 128, SEQ / 128, NBATCH), 256, 0, stream>>>(
          pmat, vt, SEQ, EDIM, SEQ, z, nullptr, uv, FDIM, nullptr, nullptr,
          sP, sVT, (size_t)SEQ * EDIM, (size_t)SEQ * FDIM);
    } else {
      for (int bb = 0; bb < BC; bb++) {
        int b = b0 + bb;
        const u16* uvb = uv + (size_t)bb * SEQ * FDIM;
        transpose_v<<<dim3(EDIM / 32, SEQ / 32, 1), dim3(32, 8), 0, stream>>>(uvb, vt);
        gemm_bt<1><<<dim3(SEQ / 128, SEQ / 128), 256, 0, stream>>>(
            qb + (size_t)bb * SEQ * SATT, kb + (size_t)bb * SEQ * SATT,
            SEQ, SEQ, SATT, pmat, nullptr, nullptr, 0, nullptr, nullptr,
            0, 0, 0, 0);
        gemm_bt<2><<<dim3(EDIM / 128, SEQ / 128), 256, 0, stream>>>(
            pmat, vt, SEQ, EDIM, SEQ, z + (size_t)b * SEQ * EDIM, nullptr,
            uvb, FDIM, nullptr, nullptr, 0, 0, 0, 0);
      }
    }
  }
  gemm_bt<3><<<dim3(DDIM / 128, (NBATCH * SEQ) / 128), 256, 0, stream>>>(
      z, ow_bf, NBATCH * SEQ, DDIM, EDIM, nullptr, out, nullptr, 0,
      x, res_scale, 0, 0, 0, 0);
}

// Round 3
// 316.674 us; speedup vs baseline: 1.3657x; 1.1187x over previous
//
#include <hip/hip_runtime.h>

typedef unsigned short u16;
typedef __bf16 bf16x8 __attribute__((ext_vector_type(8)));
typedef float f32x4 __attribute__((ext_vector_type(4)));

#define SEQ   2048
#define DDIM  1024
#define EDIM  2048
#define FDIM  4224   /* 2E + S_ATT */
#define SATT  128
#define NBATCH 4

__device__ __forceinline__ u16 f2bf(float f) {
  unsigned u = __float_as_uint(f);
  unsigned r = (u + 0x7fffu + ((u >> 16) & 1u)) >> 16;
  return (u16)r;
}
__device__ __forceinline__ float bf2f(u16 v) {
  return __uint_as_float(((unsigned)v) << 16);
}

// global -> LDS direct (16B per lane). LDS dest is wave-uniform base + lane*16.
__device__ __forceinline__ void gload16(const u16* g, u16* l) {
  auto gp = (const __attribute__((address_space(1))) u16*)(unsigned long long)g;
  auto lp = (__attribute__((address_space(3))) u16*)(unsigned)(unsigned long long)l;
  __builtin_amdgcn_global_load_lds(gp, lp, 16, 0, 0);
}

// ---------------- elementwise / small kernels ----------------

__global__ void cvt_bf16_kernel(const float* __restrict__ in, u16* __restrict__ out, int n4) {
  int i = blockIdx.x * blockDim.x + threadIdx.x;
  if (i >= n4) return;
  float4 v = reinterpret_cast<const float4*>(in)[i];
  unsigned p0 = (unsigned)f2bf(v.x) | ((unsigned)f2bf(v.y) << 16);
  unsigned p1 = (unsigned)f2bf(v.z) | ((unsigned)f2bf(v.w) << 16);
  uint2 pk; pk.x = p0; pk.y = p1;
  reinterpret_cast<uint2*>(out)[i] = pk;
}

__global__ void rms_kernel(const float* __restrict__ x, const float* __restrict__ ln_g,
                           u16* __restrict__ xn) {
  int row = blockIdx.x;
  int t = threadIdx.x;
  const float4* xr = reinterpret_cast<const float4*>(x + (size_t)row * DDIM);
  float4 v = xr[t];
  float s = v.x * v.x + v.y * v.y + v.z * v.z + v.w * v.w;
#pragma unroll
  for (int off = 32; off > 0; off >>= 1) s += __shfl_down(s, off);
  __shared__ float wsum[4];
  int lane = t & 63, wv = t >> 6;
  if (lane == 0) wsum[wv] = s;
  __syncthreads();
  float tot = wsum[0] + wsum[1] + wsum[2] + wsum[3];
  float rms = sqrtf(tot * (1.0f / (float)DDIM));
  float scale = ln_g[0] / fmaxf(rms, 1e-5f);
  unsigned p0 = (unsigned)f2bf(v.x * scale) | ((unsigned)f2bf(v.y * scale) << 16);
  unsigned p1 = (unsigned)f2bf(v.z * scale) | ((unsigned)f2bf(v.w * scale) << 16);
  uint2 pk; pk.x = p0; pk.y = p1;
  reinterpret_cast<uint2*>(xn + (size_t)row * DDIM)[t] = pk;
}

__global__ void qk_kernel(const u16* __restrict__ uv, const float* __restrict__ pos_enc,
                          const float* __restrict__ gamma, const float* __restrict__ beta,
                          u16* __restrict__ q, u16* __restrict__ k) {
  int r = blockIdx.x;
  int t = threadIdx.x;
  int s = r & (SEQ - 1);
  float bval = bf2f(uv[(size_t)r * FDIM + 2 * EDIM + t]);
  float pe = pos_enc[(size_t)s * SATT + t];
  float qv = bval * gamma[t] + beta[t] + pe;
  float kv = bval * gamma[SATT + t] + beta[SATT + t] + pe;
  q[(size_t)r * SATT + t] = f2bf(qv);
  k[(size_t)r * SATT + t] = f2bf(kv);
}

// vt[b][e][s] = uv[b][s][E + e]
__global__ void transpose_v(const u16* __restrict__ uv, u16* __restrict__ vt) {
  __shared__ u16 tile[32][33];
  int b = blockIdx.z;
  uv += (size_t)b * SEQ * FDIM;
  vt += (size_t)b * EDIM * SEQ;
  int e0 = blockIdx.x * 32, s0 = blockIdx.y * 32;
  int tx = threadIdx.x, ty = threadIdx.y;
#pragma unroll
  for (int j = 0; j < 32; j += 8)
    tile[ty + j][tx] = uv[(size_t)(s0 + ty + j) * FDIM + EDIM + e0 + tx];
  __syncthreads();
#pragma unroll
  for (int j = 0; j < 32; j += 8)
    vt[(size_t)(e0 + ty + j) * SEQ + s0 + tx] = tile[tx][ty + j];
}

// ======== deep-pipeline GEMM: C(M,N) = A(M,K)*B(N,K)^T ========
// BM=256 BN=128 BK=64, 512 thr = 8 waves (4M x 2N), per-wave 64x64.
// 3-slot LDS ring (48KB/slot = A[2][128][64] + B[128][64]); compute tile t
// from slot t%3 while staging tile t+2 into slot (t+2)%3 (dead since t-1).
// 4 phases/K-tile: {ds_reads | stage 1 unit -> barrier -> setprio -> 8 MFMA
// -> barrier}; counted vmcnt(6) once per K-tile. LDS reads XOR-swizzled
// (byte ^= (row&7)<<4); inverse swizzle applied to global stage source.
template <int EPI>
__global__ __launch_bounds__(512, 2) void gemm_bt2(
    const u16* __restrict__ A, const u16* __restrict__ B,
    int M, int N, int K,
    u16* __restrict__ Cbf, float* __restrict__ Cf,
    const u16* __restrict__ U, int ldu,
    const float* __restrict__ Xres, const float* __restrict__ rscale,
    size_t sA, size_t sB, size_t sC, size_t sU) {
  __shared__ u16 lds[3 * 24576];  // 144 KiB
  const int tid = threadIdx.x;
  const int w = tid >> 6, l = tid & 63;
  const int wr = w >> 1, wc = w & 1;
  const int fr = l & 15, kg = l >> 4;

  const int bz = blockIdx.z;
  A += (size_t)bz * sA; B += (size_t)bz * sB; U += (size_t)bz * sU;

  // XCD-aware bijective swizzle (nwg % 8 == 0 for all launched shapes)
  const int nbx = gridDim.x;
  int li = blockIdx.y * nbx + blockIdx.x;
  const int cpx = (nbx * gridDim.y) >> 3;
  li = (li & 7) * cpx + (li >> 3);
  const int bn = li % nbx;
  const int bm = li / nbx;

  const int NT = K >> 6;
  const int srow = (w << 3) + (l >> 3);                // 0..63 (+L*64)
  const int scol = (((l & 7) ^ (l >> 3)) & 7) << 3;    // inverse-swizzled col
  const size_t aoff = (size_t)bm * 256 * K;
  const size_t boff = (size_t)bn * 128 * K;
  const char* ldsC = (const char*)lds;

  auto stageAu = [&](int t, int h) {
    int sb = (t % 3) * 24576 + h * 8192;
    const u16* g = A + aoff + (size_t)(h * 128 + srow) * K + t * 64 + scol;
#pragma unroll
    for (int L = 0; L < 2; L++)
      gload16(g + (size_t)(L * 64) * K, &lds[sb + (L * 8 + w) * 512]);
  };
  auto stageBu = [&](int t) {
    int sb = (t % 3) * 24576 + 16384;
    const u16* g = B + boff + (size_t)srow * K + t * 64 + scol;
#pragma unroll
    for (int L = 0; L < 2; L++)
      gload16(g + (size_t)(L * 64) * K, &lds[sb + (L * 8 + w) * 512]);
  };
  auto ldA = [&](int cur, int i, int s) -> bf16x8 {
    int r = ((wr & 1) << 6) + (i << 4) + fr;
    int off = cur * 49152 + ((wr >> 1) << 14) + (r << 7) + (s << 6) + (kg << 4);
    off ^= (r & 7) << 4;
    return *(const bf16x8*)(ldsC + off);
  };
  auto ldB = [&](int cur, int j, int s) -> bf16x8 {
    int r = (wc << 6) + (j << 4) + fr;
    int off = cur * 49152 + 32768 + (r << 7) + (s << 6) + (kg << 4);
    off ^= (r & 7) << 4;
    return *(const bf16x8*)(ldsC + off);
  };

  f32x4 acc[4][4];
#pragma unroll
  for (int i = 0; i < 4; i++)
#pragma unroll
    for (int j = 0; j < 4; j++) acc[i][j] = f32x4{0.f, 0.f, 0.f, 0.f};

  // prologue: stage tiles 0 and 1
  stageAu(0, 0); stageAu(0, 1); stageBu(0);
  if (NT > 1) { stageAu(1, 0); stageAu(1, 1); stageBu(1); }
  asm volatile("s_waitcnt vmcnt(6)" ::: "memory");
  __builtin_amdgcn_s_barrier();

  bf16x8 aF[2][2], bF[2][2][2];
  for (int t = 0; t < NT; ++t) {
    const int cur = t % 3;
    const bool st = (t + 2 < NT);
    // ---- phase 0: read A(i0,i1)+B(j0,j1); stage A-h0(t+2); MFMA q(0,0)
#pragma unroll
    for (int i = 0; i < 2; i++)
#pragma unroll
      for (int s = 0; s < 2; s++) aF[i][s] = ldA(cur, i, s);
#pragma unroll
    for (int j = 0; j < 2; j++)
#pragma unroll
      for (int s = 0; s < 2; s++) bF[0][j][s] = ldB(cur, j, s);
    if (st) stageAu(t + 2, 0);
    __builtin_amdgcn_s_barrier();
    __builtin_amdgcn_s_setprio(1);
#pragma unroll
    for (int s = 0; s < 2; s++)
#pragma unroll
      for (int i = 0; i < 2; i++)
#pragma unroll
        for (int j = 0; j < 2; j++)
          acc[i][j] = __builtin_amdgcn_mfma_f32_16x16x32_bf16(aF[i][s], bF[0][j][s], acc[i][j], 0, 0, 0);
    __builtin_amdgcn_s_setprio(0);
    __builtin_amdgcn_s_barrier();
    // ---- phase 1: read B(j2,j3); stage A-h1(t+2); MFMA q(0,1)
#pragma unroll
    for (int j = 0; j < 2; j++)
#pragma unroll
      for (int s = 0; s < 2; s++) bF[1][j][s] = ldB(cur, 2 + j, s);
    if (st) stageAu(t + 2, 1);
    __builtin_amdgcn_s_barrier();
    __builtin_amdgcn_s_setprio(1);
#pragma unroll
    for (int s = 0; s < 2; s++)
#pragma unroll
      for (int i = 0; i < 2; i++)
#pragma unroll
        for (int j = 0; j < 2; j++)
          acc[i][2 + j] = __builtin_amdgcn_mfma_f32_16x16x32_bf16(aF[i][s], bF[1][j][s], acc[i][2 + j], 0, 0, 0);
    __builtin_amdgcn_s_setprio(0);
    __builtin_amdgcn_s_barrier();
    // ---- phase 2: read A(i2,i3); stage B(t+2); MFMA q(1,0)
#pragma unroll
    for (int i = 0; i < 2; i++)
#pragma unroll
      for (int s = 0; s < 2; s++) aF[i][s] = ldA(cur, 2 + i, s);
    if (st) stageBu(t + 2);
    __builtin_amdgcn_s_barrier();
    __builtin_amdgcn_s_setprio(1);
#pragma unroll
    for (int s = 0; s < 2; s++)
#pragma unroll
      for (int i = 0; i < 2; i++)
#pragma unroll
        for (int j = 0; j < 2; j++)
          acc[2 + i][j] = __builtin_amdgcn_mfma_f32_16x16x32_bf16(aF[i][s], bF[0][j][s], acc[2 + i][j], 0, 0, 0);
    __builtin_amdgcn_s_setprio(0);
    __builtin_amdgcn_s_barrier();
    // ---- phase 3: MFMA q(1,1); counted vmcnt; tile-boundary barrier
    __builtin_amdgcn_s_setprio(1);
#pragma unroll
    for (int s = 0; s < 2; s++)
#pragma unroll
      for (int i = 0; i < 2; i++)
#pragma unroll
        for (int j = 0; j < 2; j++)
          acc[2 + i][2 + j] = __builtin_amdgcn_mfma_f32_16x16x32_bf16(aF[i][s], bF[1][j][s], acc[2 + i][2 + j], 0, 0, 0);
    __builtin_amdgcn_s_setprio(0);
    if (st) asm volatile("s_waitcnt vmcnt(6)" ::: "memory");
    else    asm volatile("s_waitcnt vmcnt(0)" ::: "memory");
    __builtin_amdgcn_s_barrier();
  }

  // epilogue
  const int m0 = bm * 256 + wr * 64;
  const int n0 = bn * 128 + wc * 64;
  const int rsub = (l >> 4) * 4;
  const int ccol = l & 15;
#pragma unroll
  for (int i = 0; i < 4; i++) {
#pragma unroll
    for (int j = 0; j < 4; j++) {
      int n = n0 + j * 16 + ccol;
#pragma unroll
      for (int tt = 0; tt < 4; tt++) {
        int m = m0 + i * 16 + rsub + tt;
        float v = acc[i][j][tt];
        size_t idx = (size_t)m * N + n;
        if constexpr (EPI == 0) {
          float sv = v / (1.f + __expf(-v));
          Cbf[(size_t)bz * sC + idx] = f2bf(sv);
        } else if constexpr (EPI == 1) {
          float sc = v * 0.08838834764831845f;  // 1/sqrt(128)
          sc = sc > 0.f ? sc * sc : 0.f;
          Cbf[(size_t)bz * sC + idx] = f2bf(sc);
        } else if constexpr (EPI == 2) {
          float uvl = bf2f(U[(size_t)m * ldu + n]);
          Cbf[(size_t)bz * sC + idx] = f2bf(v * uvl);
        } else {
          Cf[idx] = Xres[idx] * rscale[n] + v;
        }
      }
    }
  }
}

// ---------------- legacy 128x128 GEMM (fallback path only) ----------------
template <int EPI>
__global__ __launch_bounds__(256) void gemm_bt(
    const u16* __restrict__ A, const u16* __restrict__ B,
    int M, int N, int K,
    u16* __restrict__ Cbf, float* __restrict__ Cf,
    const u16* __restrict__ U, int ldu,
    const float* __restrict__ Xres, const float* __restrict__ rscale,
    size_t sA, size_t sB, size_t sC, size_t sU) {
  __shared__ u16 As[128 * 32];
  __shared__ u16 Bs[128 * 32];
  const int tid = threadIdx.x;
  const int wave = tid >> 6, lane = tid & 63;
  const int wr = wave >> 1, wc = wave & 1;
  const int bz = blockIdx.z;
  A += (size_t)bz * sA; B += (size_t)bz * sB; U += (size_t)bz * sU;
  const int nbx = gridDim.x;
  int li = blockIdx.y * nbx + blockIdx.x;
  const int cpx = (nbx * gridDim.y) >> 3;
  li = (li & 7) * cpx + (li >> 3);
  const int bn = li % nbx;
  const int bm = li / nbx;
  const size_t abase = (size_t)bm * 128 * K;
  const size_t bbase = (size_t)bn * 128 * K;
  const int srow = tid >> 2;
  const int scol = (tid & 3) * 8;
  f32x4 acc[4][4];
#pragma unroll
  for (int i = 0; i < 4; i++)
#pragma unroll
    for (int j = 0; j < 4; j++) acc[i][j] = f32x4{0.f, 0.f, 0.f, 0.f};
  const int fr = lane & 15;
  const int fk = (lane >> 4) * 8;
  for (int k0 = 0; k0 < K; k0 += 32) {
#pragma unroll
    for (int r = 0; r < 2; r++) {
      const u16* gA = A + abase + (size_t)(r * 64 + srow) * K + k0 + scol;
      const u16* gB = B + bbase + (size_t)(r * 64 + srow) * K + k0 + scol;
      gload16(gA, As + r * 2048 + wave * 512);
      gload16(gB, Bs + r * 2048 + wave * 512);
    }
    __syncthreads();
    bf16x8 af[4], bfr[4];
#pragma unroll
    for (int i = 0; i < 4; i++) {
      af[i]  = *reinterpret_cast<const bf16x8*>(&As[(wr * 64 + i * 16 + fr) * 32 + fk]);
      bfr[i] = *reinterpret_cast<const bf16x8*>(&Bs[(wc * 64 + i * 16 + fr) * 32 + fk]);
    }
#pragma unroll
    for (int i = 0; i < 4; i++)
#pragma unroll
      for (int j = 0; j < 4; j++)
        acc[i][j] = __builtin_amdgcn_mfma_f32_16x16x32_bf16(af[i], bfr[j], acc[i][j], 0, 0, 0);
    __syncthreads();
  }
  const int m0 = bm * 128 + wr * 64;
  const int n0 = bn * 128 + wc * 64;
  const int rsub = (lane >> 4) * 4;
  const int ccol = lane & 15;
#pragma unroll
  for (int i = 0; i < 4; i++) {
#pragma unroll
    for (int j = 0; j < 4; j++) {
      int n = n0 + j * 16 + ccol;
#pragma unroll
      for (int t = 0; t < 4; t++) {
        int m = m0 + i * 16 + rsub + t;
        float v = acc[i][j][t];
        size_t idx = (size_t)m * N + n;
        if constexpr (EPI == 0) {
          float sv = v / (1.f + __expf(-v));
          Cbf[(size_t)bz * sC + idx] = f2bf(sv);
        } else if constexpr (EPI == 1) {
          float sc = v * 0.08838834764831845f;
          sc = sc > 0.f ? sc * sc : 0.f;
          Cbf[(size_t)bz * sC + idx] = f2bf(sc);
        } else if constexpr (EPI == 2) {
          float uvl = bf2f(U[(size_t)m * ldu + n]);
          Cbf[(size_t)bz * sC + idx] = f2bf(v * uvl);
        } else {
          Cf[idx] = Xres[idx] * rscale[n] + v;
        }
      }
    }
  }
}

// ---------------- launcher ----------------

extern "C" void kernel_launch(void* const* d_in, const int* in_sizes, int n_in,
                              void* d_out, int out_size, void* d_ws, size_t ws_size,
                              hipStream_t stream) {
  const float* x        = (const float*)d_in[0];
  const float* pos_enc  = (const float*)d_in[1];
  const float* uv_w     = (const float*)d_in[2];
  const float* o_w      = (const float*)d_in[3];
  const float* gamma    = (const float*)d_in[4];
  const float* beta     = (const float*)d_in[5];
  const float* ln_g     = (const float*)d_in[6];
  const float* res_scale= (const float*)d_in[7];
  float* out = (float*)d_out;

  const size_t SZ_UVW  = (size_t)FDIM * DDIM * 2;
  const size_t SZ_OW   = (size_t)DDIM * EDIM * 2;
  const size_t SZ_Z    = (size_t)NBATCH * SEQ * EDIM * 2;
  const size_t SZ_XN   = (size_t)NBATCH * SEQ * DDIM * 2;
  const size_t SZ_UV   = (size_t)NBATCH * SEQ * FDIM * 2;
  const size_t SZ_QK   = (size_t)NBATCH * SEQ * SATT * 2;
  const size_t SZ_VT1  = (size_t)EDIM * SEQ * 2;
  const size_t SZ_P1   = (size_t)SEQ * SEQ * 2;
  auto al = [](size_t b) { return (b + 255) & ~(size_t)255; };
  const size_t need_full =
      al(SZ_UVW) + al(SZ_OW) + al(SZ_Z) + al(SZ_XN) + al(SZ_UV) + 2 * al(SZ_QK) +
      (size_t)NBATCH * (al(SZ_VT1) + al(SZ_P1));
  const bool FULL = ws_size >= need_full;

  char* p = (char*)d_ws;
  auto alloc = [&](size_t bytes) {
    char* r = p;
    p += (bytes + 255) & ~(size_t)255;
    return r;
  };
  u16* uvw_bf = (u16*)alloc(SZ_UVW);
  u16* ow_bf  = (u16*)alloc(SZ_OW);
  u16* z      = (u16*)alloc(SZ_Z);
  u16* vt     = (u16*)alloc(FULL ? (size_t)NBATCH * al(SZ_VT1) : SZ_VT1);
  u16* pmat   = (u16*)alloc(FULL ? (size_t)NBATCH * al(SZ_P1) : SZ_P1);
  size_t fixed = (size_t)(p - (char*)d_ws);
  const size_t perbc = (size_t)SEQ * DDIM * 2 + (size_t)SEQ * FDIM * 2 +
                       2 * (size_t)SEQ * SATT * 2 + 4 * 256;
  int BC = FULL ? NBATCH : ((ws_size >= fixed + 4 * perbc) ? 4 : 1);
  u16* xn = (u16*)alloc((size_t)BC * SEQ * DDIM * 2);
  u16* uv = (u16*)alloc((size_t)BC * SEQ * FDIM * 2);
  u16* qb = (u16*)alloc((size_t)BC * SEQ * SATT * 2);
  u16* kb = (u16*)alloc((size_t)BC * SEQ * SATT * 2);

  const size_t sVT = (al(SZ_VT1) >> 1);
  const size_t sP  = (al(SZ_P1) >> 1);

  {
    int n4 = FDIM * DDIM / 4;
    cvt_bf16_kernel<<<(n4 + 255) / 256, 256, 0, stream>>>(uv_w, uvw_bf, n4);
    n4 = DDIM * EDIM / 4;
    cvt_bf16_kernel<<<(n4 + 255) / 256, 256, 0, stream>>>(o_w, ow_bf, n4);
  }

  if (FULL) {
    const int rows = NBATCH * SEQ;   // 8192
    rms_kernel<<<rows, 256, 0, stream>>>(x, ln_g, xn);
    gemm_bt2<0><<<dim3(FDIM / 128, rows / 256), 512, 0, stream>>>(
        xn, uvw_bf, rows, FDIM, DDIM, uv, nullptr, nullptr, 0, nullptr, nullptr,
        0, 0, 0, 0);
    qk_kernel<<<rows, SATT, 0, stream>>>(uv, pos_enc, gamma, beta, qb, kb);
    transpose_v<<<dim3(EDIM / 32, SEQ / 32, NBATCH), dim3(32, 8), 0, stream>>>(uv, vt);
    gemm_bt2<1><<<dim3(SEQ / 128, SEQ / 256, NBATCH), 512, 0, stream>>>(
        qb, kb, SEQ, SEQ, SATT, pmat, nullptr, nullptr, 0, nullptr, nullptr,
        (size_t)SEQ * SATT, (size_t)SEQ * SATT, sP, 0);
    gemm_bt2<2><<<dim3(EDIM / 128, SEQ / 256, NBATCH), 512, 0, stream>>>(
        pmat, vt, SEQ, EDIM, SEQ, z, nullptr, uv, FDIM, nullptr, nullptr,
        sP, sVT, (size_t)SEQ * EDIM, (size_t)SEQ * FDIM);
    gemm_bt2<3><<<dim3(DDIM / 128, rows / 256), 512, 0, stream>>>(
        z, ow_bf, rows, DDIM, EDIM, nullptr, out, nullptr, 0,
        x, res_scale, 0, 0, 0, 0);
  } else {
    for (int b0 = 0; b0 < NBATCH; b0 += BC) {
      int rows = BC * SEQ;
      rms_kernel<<<rows, 256, 0, stream>>>(x + (size_t)b0 * SEQ * DDIM, ln_g, xn);
      gemm_bt<0><<<dim3(FDIM / 128, rows / 128), 256, 0, stream>>>(
          xn, uvw_bf, rows, FDIM, DDIM, uv, nullptr, nullptr, 0, nullptr, nullptr,
          0, 0, 0, 0);
      qk_kernel<<<rows, SATT, 0, stream>>>(uv, pos_enc, gamma, beta, qb, kb);
      for (int bb = 0; bb < BC; bb++) {
        int b = b0 + bb;
        const u16* uvb = uv + (size_t)bb * SEQ * FDIM;
        transpose_v<<<dim3(EDIM / 32, SEQ / 32, 1), dim3(32, 8), 0, stream>>>(uvb, vt);
        gemm_bt<1><<<dim3(SEQ / 128, SEQ / 128), 256, 0, stream>>>(
            qb + (size_t)bb * SEQ * SATT, kb + (size_t)bb * SEQ * SATT,
            SEQ, SEQ, SATT, pmat, nullptr, nullptr, 0, nullptr, nullptr,
            0, 0, 0, 0);
        gemm_bt<2><<<dim3(EDIM / 128, SEQ / 128), 256, 0, stream>>>(
            pmat, vt, SEQ, EDIM, SEQ, z + (size_t)b * SEQ * EDIM, nullptr,
            uvb, FDIM, nullptr, nullptr, 0, 0, 0, 0);
      }
    }
    gemm_bt<3><<<dim3(DDIM / 128, (NBATCH * SEQ) / 128), 256, 0, stream>>>(
        z, ow_bf, NBATCH * SEQ, DDIM, EDIM, nullptr, out, nullptr, 0,
        x, res_scale, 0, 0, 0, 0);
  }
}

// Round 5
// 298.281 us; speedup vs baseline: 1.4499x; 1.0617x over previous
//
#include <hip/hip_runtime.h>

typedef unsigned short u16;
typedef __bf16 bf16x8 __attribute__((ext_vector_type(8)));
typedef float f32x4 __attribute__((ext_vector_type(4)));

#define SEQ   2048
#define DDIM  1024
#define EDIM  2048
#define FDIM  4224   /* 2E + S_ATT */
#define FPAD  4352   /* FDIM padded to 17*256 */
#define SATT  128
#define NBATCH 4

__device__ __forceinline__ u16 f2bf(float f) {
  unsigned u = __float_as_uint(f);
  unsigned r = (u + 0x7fffu + ((u >> 16) & 1u)) >> 16;
  return (u16)r;
}
__device__ __forceinline__ float bf2f(u16 v) {
  return __uint_as_float(((unsigned)v) << 16);
}

__device__ __forceinline__ void gload16(const u16* g, u16* l) {
  auto gp = (const __attribute__((address_space(1))) u16*)(unsigned long long)g;
  auto lp = (__attribute__((address_space(3))) u16*)(unsigned)(unsigned long long)l;
  __builtin_amdgcn_global_load_lds(gp, lp, 16, 0, 0);
}

// ---------------- elementwise / small kernels ----------------

__global__ void cvt_bf16_kernel(const float* __restrict__ in, u16* __restrict__ out, int n4) {
  int i = blockIdx.x * blockDim.x + threadIdx.x;
  if (i >= n4) return;
  float4 v = reinterpret_cast<const float4*>(in)[i];
  unsigned p0 = (unsigned)f2bf(v.x) | ((unsigned)f2bf(v.y) << 16);
  unsigned p1 = (unsigned)f2bf(v.z) | ((unsigned)f2bf(v.w) << 16);
  uint2 pk; pk.x = p0; pk.y = p1;
  reinterpret_cast<uint2*>(out)[i] = pk;
}

__global__ void rms_kernel(const float* __restrict__ x, const float* __restrict__ ln_g,
                           u16* __restrict__ xn) {
  int row = blockIdx.x;
  int t = threadIdx.x;
  const float4* xr = reinterpret_cast<const float4*>(x + (size_t)row * DDIM);
  float4 v = xr[t];
  float s = v.x * v.x + v.y * v.y + v.z * v.z + v.w * v.w;
#pragma unroll
  for (int off = 32; off > 0; off >>= 1) s += __shfl_down(s, off);
  __shared__ float wsum[4];
  int lane = t & 63, wv = t >> 6;
  if (lane == 0) wsum[wv] = s;
  __syncthreads();
  float tot = wsum[0] + wsum[1] + wsum[2] + wsum[3];
  float rms = sqrtf(tot * (1.0f / (float)DDIM));
  float scale = ln_g[0] / fmaxf(rms, 1e-5f);
  unsigned p0 = (unsigned)f2bf(v.x * scale) | ((unsigned)f2bf(v.y * scale) << 16);
  unsigned p1 = (unsigned)f2bf(v.z * scale) | ((unsigned)f2bf(v.w * scale) << 16);
  uint2 pk; pk.x = p0; pk.y = p1;
  reinterpret_cast<uint2*>(xn + (size_t)row * DDIM)[t] = pk;
}

__global__ void qk_kernel(const u16* __restrict__ uv, const float* __restrict__ pos_enc,
                          const float* __restrict__ gamma, const float* __restrict__ beta,
                          u16* __restrict__ q, u16* __restrict__ k, int ldF) {
  int r = blockIdx.x;
  int t = threadIdx.x;
  int s = r & (SEQ - 1);
  float bval = bf2f(uv[(size_t)r * ldF + 2 * EDIM + t]);
  float pe = pos_enc[(size_t)s * SATT + t];
  float qv = bval * gamma[t] + beta[t] + pe;
  float kv = bval * gamma[SATT + t] + beta[SATT + t] + pe;
  q[(size_t)r * SATT + t] = f2bf(qv);
  k[(size_t)r * SATT + t] = f2bf(kv);
}

// vt[b][e][s] = uv[b][s][E + e]
__global__ void transpose_v(const u16* __restrict__ uv, u16* __restrict__ vt, int ldF) {
  __shared__ u16 tile[32][33];
  int b = blockIdx.z;
  uv += (size_t)b * SEQ * ldF;
  vt += (size_t)b * EDIM * SEQ;
  int e0 = blockIdx.x * 32, s0 = blockIdx.y * 32;
  int tx = threadIdx.x, ty = threadIdx.y;
#pragma unroll
  for (int j = 0; j < 32; j += 8)
    tile[ty + j][tx] = uv[(size_t)(s0 + ty + j) * ldF + EDIM + e0 + tx];
  __syncthreads();
#pragma unroll
  for (int j = 0; j < 32; j += 8)
    vt[(size_t)(e0 + ty + j) * SEQ + s0 + tx] = tile[tx][ty + j];
}

// ======== quadrant-phase GEMM: C(M,N) = A(M,K)*B(N,K)^T ========
// BM=BN=256, BK=64, 512 thr = 8 waves (2 wm x 4 wn).
// LDS 128 KiB = 2 dbuf x 4 panels (A-h0,A-h1,B-h0,B-h1) of 16 KiB.
// Phase p = C-quadrant (qa=p>>1, qb=p&1): 16 MFMA/wave/phase.
// Panel LDS-reads: A-h0@ph0, B-h0@ph0, B-h1@ph1, A-h1@ph2, ph3 reg-only.
// Stages target ONLY buf^1 (tile t+1): ph0->A-h0, ph1->B-h0, ph2->B-h1,
// ph3->A-h1. Counted vmcnt(4) at top of ph0/1/2 guarantees each phase's
// panels landed (4-8 loads stay in flight across barriers).
// XOR swizzle byte^=(row&7)<<4 on ds_read; inverse pre-applied to global src.
template <int EPI>
__global__ __launch_bounds__(512, 2) void gemm_bt3(
    const u16* __restrict__ A, const u16* __restrict__ B,
    int N, int K,
    u16* __restrict__ Cbf,
    const u16* __restrict__ U, int ldu,
    size_t sA, size_t sB, size_t sC, size_t sU) {
  __shared__ u16 lds[65536];  // 128 KiB
  const int tid = threadIdx.x;
  const int w = tid >> 6, l = tid & 63;
  const int wm2 = w >> 2, wn2 = w & 3;
  const int fr = l & 15, kg = l >> 4;

  const int bz = blockIdx.z;
  A += (size_t)bz * sA; B += (size_t)bz * sB; U += (size_t)bz * sU;

  // XCD-aware bijective swizzle (nwg % 8 == 0 for all launched shapes)
  const int nbx = gridDim.x;
  int li = blockIdx.y * nbx + blockIdx.x;
  const int cpx = (nbx * gridDim.y) >> 3;
  li = (li & 7) * cpx + (li >> 3);
  const int bn = li % nbx;
  const int bm = li / nbx;

  const int NT = K >> 6;
  const size_t aoff = (size_t)bm * 256 * K;
  const size_t boff = (size_t)bn * 256 * K;

  const int r0 = (w << 3) + (l >> 3);                    // staging row 0..63
  const int cswz = (((l & 7) ^ (l >> 3)) & 7) << 3;      // inv-swizzled col

  // panel p: 0=A-h0, 1=A-h1, 2=B-h0, 3=B-h1 (byte offset p*16384 within buf)
  auto stageP = [&](int T, int p) {
    int off = (T & 1) * 65536 + p * 16384;
    const u16* g;
    if (p == 0)      g = A + aoff;
    else if (p == 1) g = A + aoff + (size_t)128 * K;
    else if (p == 2) g = B + boff;
    else             g = B + boff + (size_t)128 * K;
    g += (size_t)r0 * K + (size_t)T * 64 + cswz;
    u16* dst = lds + (off >> 1) + w * 512;
    gload16(g, dst);
    gload16(g + (size_t)64 * K, dst + 4096);
  };

  const char* ldsC = (const char*)lds;
  auto ldA = [&](int buf, int qa, int i, int s) -> bf16x8 {
    int row = wm2 * 64 + i * 16 + fr;
    int off = buf * 65536 + qa * 16384 + row * 128 + s * 64 + kg * 16;
    off ^= (fr & 7) << 4;
    return *(const bf16x8*)(ldsC + off);
  };
  auto ldB = [&](int buf, int qb, int j, int s) -> bf16x8 {
    int row = wn2 * 32 + j * 16 + fr;
    int off = buf * 65536 + 32768 + qb * 16384 + row * 128 + s * 64 + kg * 16;
    off ^= (fr & 7) << 4;
    return *(const bf16x8*)(ldsC + off);
  };

  f32x4 acc[8][4];
#pragma unroll
  for (int i = 0; i < 8; i++)
#pragma unroll
    for (int j = 0; j < 4; j++) acc[i][j] = f32x4{0.f, 0.f, 0.f, 0.f};

  // prologue: stage tile 0, drain, barrier
  stageP(0, 0); stageP(0, 2); stageP(0, 3); stageP(0, 1);
  asm volatile("s_waitcnt vmcnt(0)" ::: "memory");
  __builtin_amdgcn_s_barrier();

  bf16x8 aH[4][2], bF[2][2][2];  // bF[qb][j][s]
  for (int t = 0; t < NT; ++t) {
    const int buf = t & 1;
    const bool st = (t + 1 < NT);
    // ---- phase 0: quadrant (0,0). reads A-h0 (8) + B-h0 (4); stage (t+1).A-h0
    asm volatile("s_waitcnt vmcnt(4)" ::: "memory");
#pragma unroll
    for (int i = 0; i < 4; i++)
#pragma unroll
      for (int s = 0; s < 2; s++) aH[i][s] = ldA(buf, 0, i, s);
#pragma unroll
    for (int j = 0; j < 2; j++)
#pragma unroll
      for (int s = 0; s < 2; s++) bF[0][j][s] = ldB(buf, 0, j, s);
    if (st) stageP(t + 1, 0);
    __builtin_amdgcn_s_barrier();
    asm volatile("s_waitcnt lgkmcnt(0)" ::: "memory");
    __builtin_amdgcn_s_setprio(1);
#pragma unroll
    for (int s = 0; s < 2; s++)
#pragma unroll
      for (int i = 0; i < 4; i++)
#pragma unroll
        for (int j = 0; j < 2; j++)
          acc[i][j] = __builtin_amdgcn_mfma_f32_16x16x32_bf16(aH[i][s], bF[0][j][s], acc[i][j], 0, 0, 0);
    __builtin_amdgcn_s_setprio(0);
    __builtin_amdgcn_s_barrier();
    // ---- phase 1: quadrant (0,1). reads B-h1 (4); stage (t+1).B-h0
    asm volatile("s_waitcnt vmcnt(4)" ::: "memory");
#pragma unroll
    for (int j = 0; j < 2; j++)
#pragma unroll
      for (int s = 0; s < 2; s++) bF[1][j][s] = ldB(buf, 1, j, s);
    if (st) stageP(t + 1, 2);
    __builtin_amdgcn_s_barrier();
    asm volatile("s_waitcnt lgkmcnt(0)" ::: "memory");
    __builtin_amdgcn_s_setprio(1);
#pragma unroll
    for (int s = 0; s < 2; s++)
#pragma unroll
      for (int i = 0; i < 4; i++)
#pragma unroll
        for (int j = 0; j < 2; j++)
          acc[i][2 + j] = __builtin_amdgcn_mfma_f32_16x16x32_bf16(aH[i][s], bF[1][j][s], acc[i][2 + j], 0, 0, 0);
    __builtin_amdgcn_s_setprio(0);
    __builtin_amdgcn_s_barrier();
    // ---- phase 2: quadrant (1,0). reads A-h1 (8); stage (t+1).B-h1
    asm volatile("s_waitcnt vmcnt(4)" ::: "memory");
#pragma unroll
    for (int i = 0; i < 4; i++)
#pragma unroll
      for (int s = 0; s < 2; s++) aH[i][s] = ldA(buf, 1, i, s);
    if (st) stageP(t + 1, 3);
    __builtin_amdgcn_s_barrier();
    asm volatile("s_waitcnt lgkmcnt(0)" ::: "memory");
    __builtin_amdgcn_s_setprio(1);
#pragma unroll
    for (int s = 0; s < 2; s++)
#pragma unroll
      for (int i = 0; i < 4; i++)
#pragma unroll
        for (int j = 0; j < 2; j++)
          acc[4 + i][j] = __builtin_amdgcn_mfma_f32_16x16x32_bf16(aH[i][s], bF[0][j][s], acc[4 + i][j], 0, 0, 0);
    __builtin_amdgcn_s_setprio(0);
    __builtin_amdgcn_s_barrier();
    // ---- phase 3: quadrant (1,1). reg-only; stage (t+1).A-h1
    if (st) stageP(t + 1, 1);
    __builtin_amdgcn_s_barrier();
    __builtin_amdgcn_s_setprio(1);
#pragma unroll
    for (int s = 0; s < 2; s++)
#pragma unroll
      for (int i = 0; i < 4; i++)
#pragma unroll
        for (int j = 0; j < 2; j++)
          acc[4 + i][2 + j] = __builtin_amdgcn_mfma_f32_16x16x32_bf16(aH[i][s], bF[1][j][s], acc[4 + i][2 + j], 0, 0, 0);
    __builtin_amdgcn_s_setprio(0);
    __builtin_amdgcn_s_barrier();
  }

  // epilogue
  const int rsub = (l >> 4) * 4;
  const int ccol = l & 15;
#pragma unroll
  for (int ai = 0; ai < 8; ai++) {
#pragma unroll
    for (int bj = 0; bj < 4; bj++) {
      int n = bn * 256 + (bj >> 1) * 128 + wn2 * 32 + (bj & 1) * 16 + ccol;
#pragma unroll
      for (int tt = 0; tt < 4; tt++) {
        int m = bm * 256 + (ai >> 2) * 128 + wm2 * 64 + (ai & 3) * 16 + rsub + tt;
        float v = acc[ai][bj][tt];
        size_t idx = (size_t)m * N + n;
        if constexpr (EPI == 0) {
          float sv = v / (1.f + __expf(-v));
          Cbf[(size_t)bz * sC + idx] = f2bf(sv);
        } else if constexpr (EPI == 1) {
          float sc = v * 0.08838834764831845f;  // 1/sqrt(128)
          sc = sc > 0.f ? sc * sc : 0.f;
          Cbf[(size_t)bz * sC + idx] = f2bf(sc);
        } else {
          float uvl = bf2f(U[(size_t)m * ldu + n]);
          Cbf[(size_t)bz * sC + idx] = f2bf(v * uvl);
        }
      }
    }
  }
}

// ======== 256x128 deep-pipeline GEMM (gemm3; round-3 proven) ====
template <int EPI>
__global__ __launch_bounds__(512, 2) void gemm_bt2(
    const u16* __restrict__ A, const u16* __restrict__ B,
    int M, int N, int K,
    u16* __restrict__ Cbf, float* __restrict__ Cf,
    const u16* __restrict__ U, int ldu,
    const float* __restrict__ Xres, const float* __restrict__ rscale,
    size_t sA, size_t sB, size_t sC, size_t sU) {
  __shared__ u16 lds[3 * 24576];  // 144 KiB
  const int tid = threadIdx.x;
  const int w = tid >> 6, l = tid & 63;
  const int wr = w >> 1, wc = w & 1;
  const int fr = l & 15, kg = l >> 4;

  const int bz = blockIdx.z;
  A += (size_t)bz * sA; B += (size_t)bz * sB; U += (size_t)bz * sU;

  const int nbx = gridDim.x;
  int li = blockIdx.y * nbx + blockIdx.x;
  const int cpx = (nbx * gridDim.y) >> 3;
  li = (li & 7) * cpx + (li >> 3);
  const int bn = li % nbx;
  const int bm = li / nbx;

  const int NT = K >> 6;
  const int srow = (w << 3) + (l >> 3);
  const int scol = (((l & 7) ^ (l >> 3)) & 7) << 3;
  const size_t aoff = (size_t)bm * 256 * K;
  const size_t boff = (size_t)bn * 128 * K;
  const char* ldsC = (const char*)lds;

  auto stageAu = [&](int t, int h) {
    int sb = (t % 3) * 24576 + h * 8192;
    const u16* g = A + aoff + (size_t)(h * 128 + srow) * K + t * 64 + scol;
#pragma unroll
    for (int L = 0; L < 2; L++)
      gload16(g + (size_t)(L * 64) * K, &lds[sb + (L * 8 + w) * 512]);
  };
  auto stageBu = [&](int t) {
    int sb = (t % 3) * 24576 + 16384;
    const u16* g = B + boff + (size_t)srow * K + t * 64 + scol;
#pragma unroll
    for (int L = 0; L < 2; L++)
      gload16(g + (size_t)(L * 64) * K, &lds[sb + (L * 8 + w) * 512]);
  };
  auto ldA = [&](int cur, int i, int s) -> bf16x8 {
    int r = ((wr & 1) << 6) + (i << 4) + fr;
    int off = cur * 49152 + ((wr >> 1) << 14) + (r << 7) + (s << 6) + (kg << 4);
    off ^= (r & 7) << 4;
    return *(const bf16x8*)(ldsC + off);
  };
  auto ldB = [&](int cur, int j, int s) -> bf16x8 {
    int r = (wc << 6) + (j << 4) + fr;
    int off = cur * 49152 + 32768 + (r << 7) + (s << 6) + (kg << 4);
    off ^= (r & 7) << 4;
    return *(const bf16x8*)(ldsC + off);
  };

  f32x4 acc[4][4];
#pragma unroll
  for (int i = 0; i < 4; i++)
#pragma unroll
    for (int j = 0; j < 4; j++) acc[i][j] = f32x4{0.f, 0.f, 0.f, 0.f};

  stageAu(0, 0); stageAu(0, 1); stageBu(0);
  if (NT > 1) { stageAu(1, 0); stageAu(1, 1); stageBu(1); }
  asm volatile("s_waitcnt vmcnt(6)" ::: "memory");
  __builtin_amdgcn_s_barrier();

  bf16x8 aF[2][2], bF[2][2][2];
  for (int t = 0; t < NT; ++t) {
    const int cur = t % 3;
    const bool st = (t + 2 < NT);
#pragma unroll
    for (int i = 0; i < 2; i++)
#pragma unroll
      for (int s = 0; s < 2; s++) aF[i][s] = ldA(cur, i, s);
#pragma unroll
    for (int j = 0; j < 2; j++)
#pragma unroll
      for (int s = 0; s < 2; s++) bF[0][j][s] = ldB(cur, j, s);
    if (st) stageAu(t + 2, 0);
    __builtin_amdgcn_s_barrier();
    __builtin_amdgcn_s_setprio(1);
#pragma unroll
    for (int s = 0; s < 2; s++)
#pragma unroll
      for (int i = 0; i < 2; i++)
#pragma unroll
        for (int j = 0; j < 2; j++)
          acc[i][j] = __builtin_amdgcn_mfma_f32_16x16x32_bf16(aF[i][s], bF[0][j][s], acc[i][j], 0, 0, 0);
    __builtin_amdgcn_s_setprio(0);
    __builtin_amdgcn_s_barrier();
#pragma unroll
    for (int j = 0; j < 2; j++)
#pragma unroll
      for (int s = 0; s < 2; s++) bF[1][j][s] = ldB(cur, 2 + j, s);
    if (st) stageAu(t + 2, 1);
    __builtin_amdgcn_s_barrier();
    __builtin_amdgcn_s_setprio(1);
#pragma unroll
    for (int s = 0; s < 2; s++)
#pragma unroll
      for (int i = 0; i < 2; i++)
#pragma unroll
        for (int j = 0; j < 2; j++)
          acc[i][2 + j] = __builtin_amdgcn_mfma_f32_16x16x32_bf16(aF[i][s], bF[1][j][s], acc[i][2 + j], 0, 0, 0);
    __builtin_amdgcn_s_setprio(0);
    __builtin_amdgcn_s_barrier();
#pragma unroll
    for (int i = 0; i < 2; i++)
#pragma unroll
      for (int s = 0; s < 2; s++) aF[i][s] = ldA(cur, 2 + i, s);
    if (st) stageBu(t + 2);
    __builtin_amdgcn_s_barrier();
    __builtin_amdgcn_s_setprio(1);
#pragma unroll
    for (int s = 0; s < 2; s++)
#pragma unroll
      for (int i = 0; i < 2; i++)
#pragma unroll
        for (int j = 0; j < 2; j++)
          acc[2 + i][j] = __builtin_amdgcn_mfma_f32_16x16x32_bf16(aF[i][s], bF[0][j][s], acc[2 + i][j], 0, 0, 0);
    __builtin_amdgcn_s_setprio(0);
    __builtin_amdgcn_s_barrier();
    __builtin_amdgcn_s_setprio(1);
#pragma unroll
    for (int s = 0; s < 2; s++)
#pragma unroll
      for (int i = 0; i < 2; i++)
#pragma unroll
        for (int j = 0; j < 2; j++)
          acc[2 + i][2 + j] = __builtin_amdgcn_mfma_f32_16x16x32_bf16(aF[i][s], bF[1][j][s], acc[2 + i][2 + j], 0, 0, 0);
    __builtin_amdgcn_s_setprio(0);
    if (st) asm volatile("s_waitcnt vmcnt(6)" ::: "memory");
    else    asm volatile("s_waitcnt vmcnt(0)" ::: "memory");
    __builtin_amdgcn_s_barrier();
  }

  const int m0 = bm * 256 + wr * 64;
  const int n0 = bn * 128 + wc * 64;
  const int rsub = (l >> 4) * 4;
  const int ccol = l & 15;
#pragma unroll
  for (int i = 0; i < 4; i++) {
#pragma unroll
    for (int j = 0; j < 4; j++) {
      int n = n0 + j * 16 + ccol;
#pragma unroll
      for (int tt = 0; tt < 4; tt++) {
        int m = m0 + i * 16 + rsub + tt;
        float v = acc[i][j][tt];
        size_t idx = (size_t)m * N + n;
        if constexpr (EPI == 0) {
          float sv = v / (1.f + __expf(-v));
          Cbf[(size_t)bz * sC + idx] = f2bf(sv);
        } else if constexpr (EPI == 1) {
          float sc = v * 0.08838834764831845f;
          sc = sc > 0.f ? sc * sc : 0.f;
          Cbf[(size_t)bz * sC + idx] = f2bf(sc);
        } else if constexpr (EPI == 2) {
          float uvl = bf2f(U[(size_t)m * ldu + n]);
          Cbf[(size_t)bz * sC + idx] = f2bf(v * uvl);
        } else {
          Cf[idx] = Xres[idx] * rscale[n] + v;
        }
      }
    }
  }
}

// ---------------- legacy 128x128 GEMM (fallback path only) ----------------
template <int EPI>
__global__ __launch_bounds__(256) void gemm_bt(
    const u16* __restrict__ A, const u16* __restrict__ B,
    int M, int N, int K,
    u16* __restrict__ Cbf, float* __restrict__ Cf,
    const u16* __restrict__ U, int ldu,
    const float* __restrict__ Xres, const float* __restrict__ rscale,
    size_t sA, size_t sB, size_t sC, size_t sU) {
  __shared__ u16 As[128 * 32];
  __shared__ u16 Bs[128 * 32];
  const int tid = threadIdx.x;
  const int wave = tid >> 6, lane = tid & 63;
  const int wr = wave >> 1, wc = wave & 1;
  const int bz = blockIdx.z;
  A += (size_t)bz * sA; B += (size_t)bz * sB; U += (size_t)bz * sU;
  const int nbx = gridDim.x;
  int li = blockIdx.y * nbx + blockIdx.x;
  const int cpx = (nbx * gridDim.y) >> 3;
  li = (li & 7) * cpx + (li >> 3);
  const int bn = li % nbx;
  const int bm = li / nbx;
  const size_t abase = (size_t)bm * 128 * K;
  const size_t bbase = (size_t)bn * 128 * K;
  const int srow = tid >> 2;
  const int scol = (tid & 3) * 8;
  f32x4 acc[4][4];
#pragma unroll
  for (int i = 0; i < 4; i++)
#pragma unroll
    for (int j = 0; j < 4; j++) acc[i][j] = f32x4{0.f, 0.f, 0.f, 0.f};
  const int fr = lane & 15;
  const int fk = (lane >> 4) * 8;
  for (int k0 = 0; k0 < K; k0 += 32) {
#pragma unroll
    for (int r = 0; r < 2; r++) {
      const u16* gA = A + abase + (size_t)(r * 64 + srow) * K + k0 + scol;
      const u16* gB = B + bbase + (size_t)(r * 64 + srow) * K + k0 + scol;
      gload16(gA, As + r * 2048 + wave * 512);
      gload16(gB, Bs + r * 2048 + wave * 512);
    }
    __syncthreads();
    bf16x8 af[4], bfr[4];
#pragma unroll
    for (int i = 0; i < 4; i++) {
      af[i]  = *reinterpret_cast<const bf16x8*>(&As[(wr * 64 + i * 16 + fr) * 32 + fk]);
      bfr[i] = *reinterpret_cast<const bf16x8*>(&Bs[(wc * 64 + i * 16 + fr) * 32 + fk]);
    }
#pragma unroll
    for (int i = 0; i < 4; i++)
#pragma unroll
      for (int j = 0; j < 4; j++)
        acc[i][j] = __builtin_amdgcn_mfma_f32_16x16x32_bf16(af[i], bfr[j], acc[i][j], 0, 0, 0);
    __syncthreads();
  }
  const int m0 = bm * 128 + wr * 64;
  const int n0 = bn * 128 + wc * 64;
  const int rsub = (lane >> 4) * 4;
  const int ccol = lane & 15;
#pragma unroll
  for (int i = 0; i < 4; i++) {
#pragma unroll
    for (int j = 0; j < 4; j++) {
      int n = n0 + j * 16 + ccol;
#pragma unroll
      for (int t = 0; t < 4; t++) {
        int m = m0 + i * 16 + rsub + t;
        float v = acc[i][j][t];
        size_t idx = (size_t)m * N + n;
        if constexpr (EPI == 0) {
          float sv = v / (1.f + __expf(-v));
          Cbf[(size_t)bz * sC + idx] = f2bf(sv);
        } else if constexpr (EPI == 1) {
          float sc = v * 0.08838834764831845f;
          sc = sc > 0.f ? sc * sc : 0.f;
          Cbf[(size_t)bz * sC + idx] = f2bf(sc);
        } else if constexpr (EPI == 2) {
          float uvl = bf2f(U[(size_t)m * ldu + n]);
          Cbf[(size_t)bz * sC + idx] = f2bf(v * uvl);
        } else {
          Cf[idx] = Xres[idx] * rscale[n] + v;
        }
      }
    }
  }
}

// ---------------- launcher ----------------

extern "C" void kernel_launch(void* const* d_in, const int* in_sizes, int n_in,
                              void* d_out, int out_size, void* d_ws, size_t ws_size,
                              hipStream_t stream) {
  const float* x        = (const float*)d_in[0];
  const float* pos_enc  = (const float*)d_in[1];
  const float* uv_w     = (const float*)d_in[2];
  const float* o_w      = (const float*)d_in[3];
  const float* gamma    = (const float*)d_in[4];
  const float* beta     = (const float*)d_in[5];
  const float* ln_g     = (const float*)d_in[6];
  const float* res_scale= (const float*)d_in[7];
  float* out = (float*)d_out;

  auto al = [](size_t b) { return (b + 255) & ~(size_t)255; };
  const size_t SZ_UVWP = (size_t)FPAD * DDIM * 2;
  const size_t SZ_OW   = (size_t)DDIM * EDIM * 2;
  const size_t SZ_Z    = (size_t)NBATCH * SEQ * EDIM * 2;
  const size_t SZ_XN   = (size_t)NBATCH * SEQ * DDIM * 2;
  const size_t SZ_UVP  = (size_t)NBATCH * SEQ * FPAD * 2;
  const size_t SZ_QK   = (size_t)NBATCH * SEQ * SATT * 2;
  const size_t SZ_VT1  = (size_t)EDIM * SEQ * 2;
  const size_t SZ_P1   = (size_t)SEQ * SEQ * 2;
  const size_t need_full =
      al(SZ_UVWP) + al(SZ_OW) + al(SZ_Z) + al(SZ_XN) + al(SZ_UVP) + 2 * al(SZ_QK) +
      (size_t)NBATCH * (al(SZ_VT1) + al(SZ_P1));
  const bool FULL = ws_size >= need_full;

  char* p = (char*)d_ws;
  auto alloc = [&](size_t bytes) {
    char* r = p;
    p += (bytes + 255) & ~(size_t)255;
    return r;
  };

  if (FULL) {
    u16* uvw_bf = (u16*)alloc(SZ_UVWP);
    u16* ow_bf  = (u16*)alloc(SZ_OW);
    u16* z      = (u16*)alloc(SZ_Z);
    u16* vt     = (u16*)alloc((size_t)NBATCH * al(SZ_VT1));
    u16* pmat   = (u16*)alloc((size_t)NBATCH * al(SZ_P1));
    u16* xn     = (u16*)alloc(SZ_XN);
    u16* uv     = (u16*)alloc(SZ_UVP);
    u16* qb     = (u16*)alloc(SZ_QK);
    u16* kb     = (u16*)alloc(SZ_QK);
    const size_t sVT = al(SZ_VT1) >> 1;
    const size_t sP  = al(SZ_P1) >> 1;
    const int rows = NBATCH * SEQ;  // 8192

    hipMemsetAsync(uvw_bf + (size_t)FDIM * DDIM, 0,
                   (size_t)(FPAD - FDIM) * DDIM * 2, stream);
    cvt_bf16_kernel<<<(FDIM * DDIM / 4 + 255) / 256, 256, 0, stream>>>(
        uv_w, uvw_bf, FDIM * DDIM / 4);
    cvt_bf16_kernel<<<(DDIM * EDIM / 4 + 255) / 256, 256, 0, stream>>>(
        o_w, ow_bf, DDIM * EDIM / 4);

    rms_kernel<<<rows, 256, 0, stream>>>(x, ln_g, xn);
    gemm_bt3<0><<<dim3(FPAD / 256, rows / 256), 512, 0, stream>>>(
        xn, uvw_bf, FPAD, DDIM, uv, nullptr, 0, 0, 0, 0, 0);
    qk_kernel<<<rows, SATT, 0, stream>>>(uv, pos_enc, gamma, beta, qb, kb, FPAD);
    transpose_v<<<dim3(EDIM / 32, SEQ / 32, NBATCH), dim3(32, 8), 0, stream>>>(uv, vt, FPAD);
    gemm_bt3<1><<<dim3(SEQ / 256, SEQ / 256, NBATCH), 512, 0, stream>>>(
        qb, kb, SEQ, SATT, pmat, nullptr, 0,
        (size_t)SEQ * SATT, (size_t)SEQ * SATT, sP, 0);
    gemm_bt3<2><<<dim3(EDIM / 256, SEQ / 256, NBATCH), 512, 0, stream>>>(
        pmat, vt, EDIM, SEQ, z, uv, FPAD,
        sP, sVT, (size_t)SEQ * EDIM, (size_t)SEQ * FPAD);
    gemm_bt2<3><<<dim3(DDIM / 128, rows / 256), 512, 0, stream>>>(
        z, ow_bf, rows, DDIM, EDIM, nullptr, out, nullptr, 0,
        x, res_scale, 0, 0, 0, 0);
    return;
  }

  // ---------- fallback (small workspace): round-2 structure ----------
  u16* uvw_bf = (u16*)alloc((size_t)FDIM * DDIM * 2);
  u16* ow_bf  = (u16*)alloc(SZ_OW);
  u16* z      = (u16*)alloc(SZ_Z);
  u16* vt     = (u16*)alloc(SZ_VT1);
  u16* pmat   = (u16*)alloc(SZ_P1);
  size_t fixed = (size_t)(p - (char*)d_ws);
  const size_t perbc = (size_t)SEQ * DDIM * 2 + (size_t)SEQ * FDIM * 2 +
                       2 * (size_t)SEQ * SATT * 2 + 4 * 256;
  int BC = (ws_size >= fixed + 4 * perbc) ? 4 : 1;
  u16* xn = (u16*)alloc((size_t)BC * SEQ * DDIM * 2);
  u16* uv = (u16*)alloc((size_t)BC * SEQ * FDIM * 2);
  u16* qb = (u16*)alloc((size_t)BC * SEQ * SATT * 2);
  u16* kb = (u16*)alloc((size_t)BC * SEQ * SATT * 2);

  cvt_bf16_kernel<<<(FDIM * DDIM / 4 + 255) / 256, 256, 0, stream>>>(
      uv_w, uvw_bf, FDIM * DDIM / 4);
  cvt_bf16_kernel<<<(DDIM * EDIM / 4 + 255) / 256, 256, 0, stream>>>(
      o_w, ow_bf, DDIM * EDIM / 4);

  for (int b0 = 0; b0 < NBATCH; b0 += BC) {
    int rows = BC * SEQ;
    rms_kernel<<<rows, 256, 0, stream>>>(x + (size_t)b0 * SEQ * DDIM, ln_g, xn);
    gemm_bt<0><<<dim3(FDIM / 128, rows / 128), 256, 0, stream>>>(
        xn, uvw_bf, rows, FDIM, DDIM, uv, nullptr, nullptr, 0, nullptr, nullptr,
        0, 0, 0, 0);
    qk_kernel<<<rows, SATT, 0, stream>>>(uv, pos_enc, gamma, beta, qb, kb, FDIM);
    for (int bb = 0; bb < BC; bb++) {
      int b = b0 + bb;
      const u16* uvb = uv + (size_t)bb * SEQ * FDIM;
      transpose_v<<<dim3(EDIM / 32, SEQ / 32, 1), dim3(32, 8), 0, stream>>>(uvb, vt, FDIM);
      gemm_bt<1><<<dim3(SEQ / 128, SEQ / 128), 256, 0, stream>>>(
          qb + (size_t)bb * SEQ * SATT, kb + (size_t)bb * SEQ * SATT,
          SEQ, SEQ, SATT, pmat, nullptr, nullptr, 0, nullptr, nullptr,
          0, 0, 0, 0);
      gemm_bt<2><<<dim3(EDIM / 128, SEQ / 128), 256, 0, stream>>>(
          pmat, vt, SEQ, EDIM, SEQ, z + (size_t)b * SEQ * EDIM, nullptr,
          uvb, FDIM, nullptr, nullptr, 0, 0, 0, 0);
    }
  }
  gemm_bt<3><<<dim3(DDIM / 128, (NBATCH * SEQ) / 128), 256, 0, stream>>>(
      z, ow_bf, NBATCH * SEQ, DDIM, EDIM, nullptr, out, nullptr, 0,
      x, res_scale, 0, 0, 0, 0);
}

// Round 6
// 296.067 us; speedup vs baseline: 1.4607x; 1.0075x over previous
//
#include <hip/hip_runtime.h>

typedef unsigned short u16;
typedef __bf16 bf16x8 __attribute__((ext_vector_type(8)));
typedef float f32x4 __attribute__((ext_vector_type(4)));

#define SEQ   2048
#define DDIM  1024
#define EDIM  2048
#define FDIM  4224   /* 2E + S_ATT */
#define FPAD  4352   /* FDIM padded to 17*256 */
#define SATT  128
#define NBATCH 4

__device__ __forceinline__ u16 f2bf(float f) {
  unsigned u = __float_as_uint(f);
  unsigned r = (u + 0x7fffu + ((u >> 16) & 1u)) >> 16;
  return (u16)r;
}
__device__ __forceinline__ float bf2f(u16 v) {
  return __uint_as_float(((unsigned)v) << 16);
}

__device__ __forceinline__ void gload16(const u16* g, u16* l) {
  auto gp = (const __attribute__((address_space(1))) u16*)(unsigned long long)g;
  auto lp = (__attribute__((address_space(3))) u16*)(unsigned)(unsigned long long)l;
  __builtin_amdgcn_global_load_lds(gp, lp, 16, 0, 0);
}

// ---------------- elementwise / small kernels ----------------

__global__ void cvt_bf16_kernel(const float* __restrict__ in, u16* __restrict__ out, int n4) {
  int i = blockIdx.x * blockDim.x + threadIdx.x;
  if (i >= n4) return;
  float4 v = reinterpret_cast<const float4*>(in)[i];
  unsigned p0 = (unsigned)f2bf(v.x) | ((unsigned)f2bf(v.y) << 16);
  unsigned p1 = (unsigned)f2bf(v.z) | ((unsigned)f2bf(v.w) << 16);
  uint2 pk; pk.x = p0; pk.y = p1;
  reinterpret_cast<uint2*>(out)[i] = pk;
}

__global__ void rms_kernel(const float* __restrict__ x, const float* __restrict__ ln_g,
                           u16* __restrict__ xn) {
  int row = blockIdx.x;
  int t = threadIdx.x;
  const float4* xr = reinterpret_cast<const float4*>(x + (size_t)row * DDIM);
  float4 v = xr[t];
  float s = v.x * v.x + v.y * v.y + v.z * v.z + v.w * v.w;
#pragma unroll
  for (int off = 32; off > 0; off >>= 1) s += __shfl_down(s, off);
  __shared__ float wsum[4];
  int lane = t & 63, wv = t >> 6;
  if (lane == 0) wsum[wv] = s;
  __syncthreads();
  float tot = wsum[0] + wsum[1] + wsum[2] + wsum[3];
  float rms = sqrtf(tot * (1.0f / (float)DDIM));
  float scale = ln_g[0] / fmaxf(rms, 1e-5f);
  unsigned p0 = (unsigned)f2bf(v.x * scale) | ((unsigned)f2bf(v.y * scale) << 16);
  unsigned p1 = (unsigned)f2bf(v.z * scale) | ((unsigned)f2bf(v.w * scale) << 16);
  uint2 pk; pk.x = p0; pk.y = p1;
  reinterpret_cast<uint2*>(xn + (size_t)row * DDIM)[t] = pk;
}

__global__ void qk_kernel(const u16* __restrict__ uv, const float* __restrict__ pos_enc,
                          const float* __restrict__ gamma, const float* __restrict__ beta,
                          u16* __restrict__ q, u16* __restrict__ k, int ldF) {
  int r = blockIdx.x;
  int t = threadIdx.x;
  int s = r & (SEQ - 1);
  float bval = bf2f(uv[(size_t)r * ldF + 2 * EDIM + t]);
  float pe = pos_enc[(size_t)s * SATT + t];
  float qv = bval * gamma[t] + beta[t] + pe;
  float kv = bval * gamma[SATT + t] + beta[SATT + t] + pe;
  q[(size_t)r * SATT + t] = f2bf(qv);
  k[(size_t)r * SATT + t] = f2bf(kv);
}

// vt[b][e][s] = uv[b][s][E + e]
__global__ void transpose_v(const u16* __restrict__ uv, u16* __restrict__ vt, int ldF) {
  __shared__ u16 tile[32][33];
  int b = blockIdx.z;
  uv += (size_t)b * SEQ * ldF;
  vt += (size_t)b * EDIM * SEQ;
  int e0 = blockIdx.x * 32, s0 = blockIdx.y * 32;
  int tx = threadIdx.x, ty = threadIdx.y;
#pragma unroll
  for (int j = 0; j < 32; j += 8)
    tile[ty + j][tx] = uv[(size_t)(s0 + ty + j) * ldF + EDIM + e0 + tx];
  __syncthreads();
#pragma unroll
  for (int j = 0; j < 32; j += 8)
    vt[(size_t)(e0 + ty + j) * SEQ + s0 + tx] = tile[tx][ty + j];
}

// ======== quadrant-phase GEMM v2 (m201 panel-ring): C = A(M,K)*B(N,K)^T ====
// BM=BN=256, BK=64, 512 thr = 8 waves (2 wm x 4 wn), per-wave 128x64.
// LDS 128 KiB = 2 dbuf x 4 panels (A-h0,A-h1,B-h0,B-h1) of 16 KiB.
// Phase p = C-quadrant: 16 MFMA/wave/phase.
// Panel LDS-reads: A-h0+B-h0 @ph0, B-h1 @ph1, A-h1 @ph2, ph3 reg-only.
// Panel stages for tile t+2 go into the CURRENT buffer (t+2 has same parity),
// each issued the phase AFTER that panel's last read:
//   ph1 -> A-h0,B-h0 ; ph2 -> B-h1 ; ph3 -> A-h1.
// ONE counted vmcnt(6) per tile at the ph3 boundary: the <=6 outstanding
// loads are t+2's newest 3 panels, so ALL of t+1's panels (staged during
// t-1) plus t+2's A-h0 are guaranteed landed. Stage->use distance = 7
// phases (~3000 cyc >> 900 cyc HBM latency).
// XOR swizzle byte^=(row&7)<<4 on ds_read; inverse pre-applied to global src.
template <int EPI>
__global__ __launch_bounds__(512, 2) void gemm_bt3(
    const u16* __restrict__ A, const u16* __restrict__ B,
    int N, int K,
    u16* __restrict__ Cbf,
    const u16* __restrict__ U, int ldu,
    size_t sA, size_t sB, size_t sC, size_t sU) {
  __shared__ u16 lds[65536];  // 128 KiB
  const int tid = threadIdx.x;
  const int w = tid >> 6, l = tid & 63;
  const int wm2 = w >> 2, wn2 = w & 3;
  const int fr = l & 15, kg = l >> 4;

  const int bz = blockIdx.z;
  A += (size_t)bz * sA; B += (size_t)bz * sB; U += (size_t)bz * sU;

  // XCD-aware bijective swizzle (nwg % 8 == 0 for all launched shapes)
  const int nbx = gridDim.x;
  int li = blockIdx.y * nbx + blockIdx.x;
  const int cpx = (nbx * gridDim.y) >> 3;
  li = (li & 7) * cpx + (li >> 3);
  const int bn = li % nbx;
  const int bm = li / nbx;

  const int NT = K >> 6;
  const size_t aoff = (size_t)bm * 256 * K;
  const size_t boff = (size_t)bn * 256 * K;

  const int r0 = (w << 3) + (l >> 3);                    // staging row 0..63
  const int cswz = (((l & 7) ^ (l >> 3)) & 7) << 3;      // inv-swizzled col

  // panel p: 0=A-h0, 1=A-h1, 2=B-h0, 3=B-h1 (byte offset p*16384 within buf)
  auto stageP = [&](int T, int p) {
    int off = (T & 1) * 65536 + p * 16384;
    const u16* g;
    if (p == 0)      g = A + aoff;
    else if (p == 1) g = A + aoff + (size_t)128 * K;
    else if (p == 2) g = B + boff;
    else             g = B + boff + (size_t)128 * K;
    g += (size_t)r0 * K + (size_t)T * 64 + cswz;
    u16* dst = lds + (off >> 1) + w * 512;
    gload16(g, dst);
    gload16(g + (size_t)64 * K, dst + 4096);
  };

  const char* ldsC = (const char*)lds;
  auto ldA = [&](int buf, int qa, int i, int s) -> bf16x8 {
    int row = wm2 * 64 + i * 16 + fr;
    int off = buf * 65536 + qa * 16384 + row * 128 + s * 64 + kg * 16;
    off ^= (fr & 7) << 4;
    return *(const bf16x8*)(ldsC + off);
  };
  auto ldB = [&](int buf, int qb, int j, int s) -> bf16x8 {
    int row = wn2 * 32 + j * 16 + fr;
    int off = buf * 65536 + 32768 + qb * 16384 + row * 128 + s * 64 + kg * 16;
    off ^= (fr & 7) << 4;
    return *(const bf16x8*)(ldsC + off);
  };

  f32x4 acc[8][4];
#pragma unroll
  for (int i = 0; i < 8; i++)
#pragma unroll
    for (int j = 0; j < 4; j++) acc[i][j] = f32x4{0.f, 0.f, 0.f, 0.f};

  // prologue: stage tiles 0 and 1 completely; wait for tile 0 only
  stageP(0, 0); stageP(0, 2); stageP(0, 3); stageP(0, 1);
  if (NT > 1) {
    stageP(1, 0); stageP(1, 2); stageP(1, 3); stageP(1, 1);
    asm volatile("s_waitcnt vmcnt(8)" ::: "memory");
  } else {
    asm volatile("s_waitcnt vmcnt(0)" ::: "memory");
  }
  __builtin_amdgcn_s_barrier();

  bf16x8 aH[4][2], bF[2][2][2];  // bF[qb][j][s]
  for (int t = 0; t < NT; ++t) {
    const int buf = t & 1;
    const bool st = (t + 2 < NT);
    // ---- phase 0: quadrant (0,0). reads A-h0 (8) + B-h0 (4); no stage
#pragma unroll
    for (int i = 0; i < 4; i++)
#pragma unroll
      for (int s = 0; s < 2; s++) aH[i][s] = ldA(buf, 0, i, s);
#pragma unroll
    for (int j = 0; j < 2; j++)
#pragma unroll
      for (int s = 0; s < 2; s++) bF[0][j][s] = ldB(buf, 0, j, s);
    asm volatile("s_waitcnt lgkmcnt(8)" ::: "memory");  // 12-read phase hint
    __builtin_amdgcn_s_barrier();
    asm volatile("s_waitcnt lgkmcnt(0)" ::: "memory");
    __builtin_amdgcn_s_setprio(1);
#pragma unroll
    for (int s = 0; s < 2; s++)
#pragma unroll
      for (int i = 0; i < 4; i++)
#pragma unroll
        for (int j = 0; j < 2; j++)
          acc[i][j] = __builtin_amdgcn_mfma_f32_16x16x32_bf16(aH[i][s], bF[0][j][s], acc[i][j], 0, 0, 0);
    __builtin_amdgcn_s_setprio(0);
    __builtin_amdgcn_s_barrier();
    // ---- phase 1: quadrant (0,1). reads B-h1 (4); stage (t+2).A-h0, B-h0
#pragma unroll
    for (int j = 0; j < 2; j++)
#pragma unroll
      for (int s = 0; s < 2; s++) bF[1][j][s] = ldB(buf, 1, j, s);
    if (st) { stageP(t + 2, 0); stageP(t + 2, 2); }
    __builtin_amdgcn_s_barrier();
    asm volatile("s_waitcnt lgkmcnt(0)" ::: "memory");
    __builtin_amdgcn_s_setprio(1);
#pragma unroll
    for (int s = 0; s < 2; s++)
#pragma unroll
      for (int i = 0; i < 4; i++)
#pragma unroll
        for (int j = 0; j < 2; j++)
          acc[i][2 + j] = __builtin_amdgcn_mfma_f32_16x16x32_bf16(aH[i][s], bF[1][j][s], acc[i][2 + j], 0, 0, 0);
    __builtin_amdgcn_s_setprio(0);
    __builtin_amdgcn_s_barrier();
    // ---- phase 2: quadrant (1,0). reads A-h1 (8); stage (t+2).B-h1
#pragma unroll
    for (int i = 0; i < 4; i++)
#pragma unroll
      for (int s = 0; s < 2; s++) aH[i][s] = ldA(buf, 1, i, s);
    if (st) stageP(t + 2, 3);
    __builtin_amdgcn_s_barrier();
    asm volatile("s_waitcnt lgkmcnt(0)" ::: "memory");
    __builtin_amdgcn_s_setprio(1);
#pragma unroll
    for (int s = 0; s < 2; s++)
#pragma unroll
      for (int i = 0; i < 4; i++)
#pragma unroll
        for (int j = 0; j < 2; j++)
          acc[4 + i][j] = __builtin_amdgcn_mfma_f32_16x16x32_bf16(aH[i][s], bF[0][j][s], acc[4 + i][j], 0, 0, 0);
    __builtin_amdgcn_s_setprio(0);
    __builtin_amdgcn_s_barrier();
    // ---- phase 3: quadrant (1,1). reg-only; stage (t+2).A-h1; boundary vmcnt
    if (st) stageP(t + 2, 1);
    __builtin_amdgcn_s_setprio(1);
#pragma unroll
    for (int s = 0; s < 2; s++)
#pragma unroll
      for (int i = 0; i < 4; i++)
#pragma unroll
        for (int j = 0; j < 2; j++)
          acc[4 + i][2 + j] = __builtin_amdgcn_mfma_f32_16x16x32_bf16(aH[i][s], bF[1][j][s], acc[4 + i][2 + j], 0, 0, 0);
    __builtin_amdgcn_s_setprio(0);
    if (st) asm volatile("s_waitcnt vmcnt(6)" ::: "memory");
    else    asm volatile("s_waitcnt vmcnt(0)" ::: "memory");
    __builtin_amdgcn_s_barrier();
  }

  // epilogue
  const int rsub = (l >> 4) * 4;
  const int ccol = l & 15;
#pragma unroll
  for (int ai = 0; ai < 8; ai++) {
#pragma unroll
    for (int bj = 0; bj < 4; bj++) {
      int n = bn * 256 + (bj >> 1) * 128 + wn2 * 32 + (bj & 1) * 16 + ccol;
#pragma unroll
      for (int tt = 0; tt < 4; tt++) {
        int m = bm * 256 + (ai >> 2) * 128 + wm2 * 64 + (ai & 3) * 16 + rsub + tt;
        float v = acc[ai][bj][tt];
        size_t idx = (size_t)m * N + n;
        if constexpr (EPI == 0) {
          float sv = v / (1.f + __expf(-v));
          Cbf[(size_t)bz * sC + idx] = f2bf(sv);
        } else if constexpr (EPI == 1) {
          float sc = v * 0.08838834764831845f;  // 1/sqrt(128)
          sc = sc > 0.f ? sc * sc : 0.f;
          Cbf[(size_t)bz * sC + idx] = f2bf(sc);
        } else {
          float uvl = bf2f(U[(size_t)m * ldu + n]);
          Cbf[(size_t)bz * sC + idx] = f2bf(v * uvl);
        }
      }
    }
  }
}

// ======== 256x128 deep-pipeline GEMM (gemm3; round-3 proven) ====
template <int EPI>
__global__ __launch_bounds__(512, 2) void gemm_bt2(
    const u16* __restrict__ A, const u16* __restrict__ B,
    int M, int N, int K,
    u16* __restrict__ Cbf, float* __restrict__ Cf,
    const u16* __restrict__ U, int ldu,
    const float* __restrict__ Xres, const float* __restrict__ rscale,
    size_t sA, size_t sB, size_t sC, size_t sU) {
  __shared__ u16 lds[3 * 24576];  // 144 KiB
  const int tid = threadIdx.x;
  const int w = tid >> 6, l = tid & 63;
  const int wr = w >> 1, wc = w & 1;
  const int fr = l & 15, kg = l >> 4;

  const int bz = blockIdx.z;
  A += (size_t)bz * sA; B += (size_t)bz * sB; U += (size_t)bz * sU;

  const int nbx = gridDim.x;
  int li = blockIdx.y * nbx + blockIdx.x;
  const int cpx = (nbx * gridDim.y) >> 3;
  li = (li & 7) * cpx + (li >> 3);
  const int bn = li % nbx;
  const int bm = li / nbx;

  const int NT = K >> 6;
  const int srow = (w << 3) + (l >> 3);
  const int scol = (((l & 7) ^ (l >> 3)) & 7) << 3;
  const size_t aoff = (size_t)bm * 256 * K;
  const size_t boff = (size_t)bn * 128 * K;
  const char* ldsC = (const char*)lds;

  auto stageAu = [&](int t, int h) {
    int sb = (t % 3) * 24576 + h * 8192;
    const u16* g = A + aoff + (size_t)(h * 128 + srow) * K + t * 64 + scol;
#pragma unroll
    for (int L = 0; L < 2; L++)
      gload16(g + (size_t)(L * 64) * K, &lds[sb + (L * 8 + w) * 512]);
  };
  auto stageBu = [&](int t) {
    int sb = (t % 3) * 24576 + 16384;
    const u16* g = B + boff + (size_t)srow * K + t * 64 + scol;
#pragma unroll
    for (int L = 0; L < 2; L++)
      gload16(g + (size_t)(L * 64) * K, &lds[sb + (L * 8 + w) * 512]);
  };
  auto ldA = [&](int cur, int i, int s) -> bf16x8 {
    int r = ((wr & 1) << 6) + (i << 4) + fr;
    int off = cur * 49152 + ((wr >> 1) << 14) + (r << 7) + (s << 6) + (kg << 4);
    off ^= (r & 7) << 4;
    return *(const bf16x8*)(ldsC + off);
  };
  auto ldB = [&](int cur, int j, int s) -> bf16x8 {
    int r = (wc << 6) + (j << 4) + fr;
    int off = cur * 49152 + 32768 + (r << 7) + (s << 6) + (kg << 4);
    off ^= (r & 7) << 4;
    return *(const bf16x8*)(ldsC + off);
  };

  f32x4 acc[4][4];
#pragma unroll
  for (int i = 0; i < 4; i++)
#pragma unroll
    for (int j = 0; j < 4; j++) acc[i][j] = f32x4{0.f, 0.f, 0.f, 0.f};

  stageAu(0, 0); stageAu(0, 1); stageBu(0);
  if (NT > 1) { stageAu(1, 0); stageAu(1, 1); stageBu(1); }
  asm volatile("s_waitcnt vmcnt(6)" ::: "memory");
  __builtin_amdgcn_s_barrier();

  bf16x8 aF[2][2], bF[2][2][2];
  for (int t = 0; t < NT; ++t) {
    const int cur = t % 3;
    const bool st = (t + 2 < NT);
#pragma unroll
    for (int i = 0; i < 2; i++)
#pragma unroll
      for (int s = 0; s < 2; s++) aF[i][s] = ldA(cur, i, s);
#pragma unroll
    for (int j = 0; j < 2; j++)
#pragma unroll
      for (int s = 0; s < 2; s++) bF[0][j][s] = ldB(cur, j, s);
    if (st) stageAu(t + 2, 0);
    __builtin_amdgcn_s_barrier();
    __builtin_amdgcn_s_setprio(1);
#pragma unroll
    for (int s = 0; s < 2; s++)
#pragma unroll
      for (int i = 0; i < 2; i++)
#pragma unroll
        for (int j = 0; j < 2; j++)
          acc[i][j] = __builtin_amdgcn_mfma_f32_16x16x32_bf16(aF[i][s], bF[0][j][s], acc[i][j], 0, 0, 0);
    __builtin_amdgcn_s_setprio(0);
    __builtin_amdgcn_s_barrier();
#pragma unroll
    for (int j = 0; j < 2; j++)
#pragma unroll
      for (int s = 0; s < 2; s++) bF[1][j][s] = ldB(cur, 2 + j, s);
    if (st) stageAu(t + 2, 1);
    __builtin_amdgcn_s_barrier();
    __builtin_amdgcn_s_setprio(1);
#pragma unroll
    for (int s = 0; s < 2; s++)
#pragma unroll
      for (int i = 0; i < 2; i++)
#pragma unroll
        for (int j = 0; j < 2; j++)
          acc[i][2 + j] = __builtin_amdgcn_mfma_f32_16x16x32_bf16(aF[i][s], bF[1][j][s], acc[i][2 + j], 0, 0, 0);
    __builtin_amdgcn_s_setprio(0);
    __builtin_amdgcn_s_barrier();
#pragma unroll
    for (int i = 0; i < 2; i++)
#pragma unroll
      for (int s = 0; s < 2; s++) aF[i][s] = ldA(cur, 2 + i, s);
    if (st) stageBu(t + 2);
    __builtin_amdgcn_s_barrier();
    __builtin_amdgcn_s_setprio(1);
#pragma unroll
    for (int s = 0; s < 2; s++)
#pragma unroll
      for (int i = 0; i < 2; i++)
#pragma unroll
        for (int j = 0; j < 2; j++)
          acc[2 + i][j] = __builtin_amdgcn_mfma_f32_16x16x32_bf16(aF[i][s], bF[0][j][s], acc[2 + i][j], 0, 0, 0);
    __builtin_amdgcn_s_setprio(0);
    __builtin_amdgcn_s_barrier();
    __builtin_amdgcn_s_setprio(1);
#pragma unroll
    for (int s = 0; s < 2; s++)
#pragma unroll
      for (int i = 0; i < 2; i++)
#pragma unroll
        for (int j = 0; j < 2; j++)
          acc[2 + i][2 + j] = __builtin_amdgcn_mfma_f32_16x16x32_bf16(aF[i][s], bF[1][j][s], acc[2 + i][2 + j], 0, 0, 0);
    __builtin_amdgcn_s_setprio(0);
    if (st) asm volatile("s_waitcnt vmcnt(6)" ::: "memory");
    else    asm volatile("s_waitcnt vmcnt(0)" ::: "memory");
    __builtin_amdgcn_s_barrier();
  }

  const int m0 = bm * 256 + wr * 64;
  const int n0 = bn * 128 + wc * 64;
  const int rsub = (l >> 4) * 4;
  const int ccol = l & 15;
#pragma unroll
  for (int i = 0; i < 4; i++) {
#pragma unroll
    for (int j = 0; j < 4; j++) {
      int n = n0 + j * 16 + ccol;
#pragma unroll
      for (int tt = 0; tt < 4; tt++) {
        int m = m0 + i * 16 + rsub + tt;
        float v = acc[i][j][tt];
        size_t idx = (size_t)m * N + n;
        if constexpr (EPI == 0) {
          float sv = v / (1.f + __expf(-v));
          Cbf[(size_t)bz * sC + idx] = f2bf(sv);
        } else if constexpr (EPI == 1) {
          float sc = v * 0.08838834764831845f;
          sc = sc > 0.f ? sc * sc : 0.f;
          Cbf[(size_t)bz * sC + idx] = f2bf(sc);
        } else if constexpr (EPI == 2) {
          float uvl = bf2f(U[(size_t)m * ldu + n]);
          Cbf[(size_t)bz * sC + idx] = f2bf(v * uvl);
        } else {
          Cf[idx] = Xres[idx] * rscale[n] + v;
        }
      }
    }
  }
}

// ---------------- legacy 128x128 GEMM (fallback path only) ----------------
template <int EPI>
__global__ __launch_bounds__(256) void gemm_bt(
    const u16* __restrict__ A, const u16* __restrict__ B,
    int M, int N, int K,
    u16* __restrict__ Cbf, float* __restrict__ Cf,
    const u16* __restrict__ U, int ldu,
    const float* __restrict__ Xres, const float* __restrict__ rscale,
    size_t sA, size_t sB, size_t sC, size_t sU) {
  __shared__ u16 As[128 * 32];
  __shared__ u16 Bs[128 * 32];
  const int tid = threadIdx.x;
  const int wave = tid >> 6, lane = tid & 63;
  const int wr = wave >> 1, wc = wave & 1;
  const int bz = blockIdx.z;
  A += (size_t)bz * sA; B += (size_t)bz * sB; U += (size_t)bz * sU;
  const int nbx = gridDim.x;
  int li = blockIdx.y * nbx + blockIdx.x;
  const int cpx = (nbx * gridDim.y) >> 3;
  li = (li & 7) * cpx + (li >> 3);
  const int bn = li % nbx;
  const int bm = li / nbx;
  const size_t abase = (size_t)bm * 128 * K;
  const size_t bbase = (size_t)bn * 128 * K;
  const int srow = tid >> 2;
  const int scol = (tid & 3) * 8;
  f32x4 acc[4][4];
#pragma unroll
  for (int i = 0; i < 4; i++)
#pragma unroll
    for (int j = 0; j < 4; j++) acc[i][j] = f32x4{0.f, 0.f, 0.f, 0.f};
  const int fr = lane & 15;
  const int fk = (lane >> 4) * 8;
  for (int k0 = 0; k0 < K; k0 += 32) {
#pragma unroll
    for (int r = 0; r < 2; r++) {
      const u16* gA = A + abase + (size_t)(r * 64 + srow) * K + k0 + scol;
      const u16* gB = B + bbase + (size_t)(r * 64 + srow) * K + k0 + scol;
      gload16(gA, As + r * 2048 + wave * 512);
      gload16(gB, Bs + r * 2048 + wave * 512);
    }
    __syncthreads();
    bf16x8 af[4], bfr[4];
#pragma unroll
    for (int i = 0; i < 4; i++) {
      af[i]  = *reinterpret_cast<const bf16x8*>(&As[(wr * 64 + i * 16 + fr) * 32 + fk]);
      bfr[i] = *reinterpret_cast<const bf16x8*>(&Bs[(wc * 64 + i * 16 + fr) * 32 + fk]);
    }
#pragma unroll
    for (int i = 0; i < 4; i++)
#pragma unroll
      for (int j = 0; j < 4; j++)
        acc[i][j] = __builtin_amdgcn_mfma_f32_16x16x32_bf16(af[i], bfr[j], acc[i][j], 0, 0, 0);
    __syncthreads();
  }
  const int m0 = bm * 128 + wr * 64;
  const int n0 = bn * 128 + wc * 64;
  const int rsub = (lane >> 4) * 4;
  const int ccol = lane & 15;
#pragma unroll
  for (int i = 0; i < 4; i++) {
#pragma unroll
    for (int j = 0; j < 4; j++) {
      int n = n0 + j * 16 + ccol;
#pragma unroll
      for (int t = 0; t < 4; t++) {
        int m = m0 + i * 16 + rsub + t;
        float v = acc[i][j][t];
        size_t idx = (size_t)m * N + n;
        if constexpr (EPI == 0) {
          float sv = v / (1.f + __expf(-v));
          Cbf[(size_t)bz * sC + idx] = f2bf(sv);
        } else if constexpr (EPI == 1) {
          float sc = v * 0.08838834764831845f;
          sc = sc > 0.f ? sc * sc : 0.f;
          Cbf[(size_t)bz * sC + idx] = f2bf(sc);
        } else if constexpr (EPI == 2) {
          float uvl = bf2f(U[(size_t)m * ldu + n]);
          Cbf[(size_t)bz * sC + idx] = f2bf(v * uvl);
        } else {
          Cf[idx] = Xres[idx] * rscale[n] + v;
        }
      }
    }
  }
}

// ---------------- launcher ----------------

extern "C" void kernel_launch(void* const* d_in, const int* in_sizes, int n_in,
                              void* d_out, int out_size, void* d_ws, size_t ws_size,
                              hipStream_t stream) {
  const float* x        = (const float*)d_in[0];
  const float* pos_enc  = (const float*)d_in[1];
  const float* uv_w     = (const float*)d_in[2];
  const float* o_w      = (const float*)d_in[3];
  const float* gamma    = (const float*)d_in[4];
  const float* beta     = (const float*)d_in[5];
  const float* ln_g     = (const float*)d_in[6];
  const float* res_scale= (const float*)d_in[7];
  float* out = (float*)d_out;

  auto al = [](size_t b) { return (b + 255) & ~(size_t)255; };
  const size_t SZ_UVWP = (size_t)FPAD * DDIM * 2;
  const size_t SZ_OW   = (size_t)DDIM * EDIM * 2;
  const size_t SZ_Z    = (size_t)NBATCH * SEQ * EDIM * 2;
  const size_t SZ_XN   = (size_t)NBATCH * SEQ * DDIM * 2;
  const size_t SZ_UVP  = (size_t)NBATCH * SEQ * FPAD * 2;
  const size_t SZ_QK   = (size_t)NBATCH * SEQ * SATT * 2;
  const size_t SZ_VT1  = (size_t)EDIM * SEQ * 2;
  const size_t SZ_P1   = (size_t)SEQ * SEQ * 2;
  const size_t need_full =
      al(SZ_UVWP) + al(SZ_OW) + al(SZ_Z) + al(SZ_XN) + al(SZ_UVP) + 2 * al(SZ_QK) +
      (size_t)NBATCH * (al(SZ_VT1) + al(SZ_P1));
  const bool FULL = ws_size >= need_full;

  char* p = (char*)d_ws;
  auto alloc = [&](size_t bytes) {
    char* r = p;
    p += (bytes + 255) & ~(size_t)255;
    return r;
  };

  if (FULL) {
    u16* uvw_bf = (u16*)alloc(SZ_UVWP);
    u16* ow_bf  = (u16*)alloc(SZ_OW);
    u16* z      = (u16*)alloc(SZ_Z);
    u16* vt     = (u16*)alloc((size_t)NBATCH * al(SZ_VT1));
    u16* pmat   = (u16*)alloc((size_t)NBATCH * al(SZ_P1));
    u16* xn     = (u16*)alloc(SZ_XN);
    u16* uv     = (u16*)alloc(SZ_UVP);
    u16* qb     = (u16*)alloc(SZ_QK);
    u16* kb     = (u16*)alloc(SZ_QK);
    const size_t sVT = al(SZ_VT1) >> 1;
    const size_t sP  = al(SZ_P1) >> 1;
    const int rows = NBATCH * SEQ;  // 8192

    hipMemsetAsync(uvw_bf + (size_t)FDIM * DDIM, 0,
                   (size_t)(FPAD - FDIM) * DDIM * 2, stream);
    cvt_bf16_kernel<<<(FDIM * DDIM / 4 + 255) / 256, 256, 0, stream>>>(
        uv_w, uvw_bf, FDIM * DDIM / 4);
    cvt_bf16_kernel<<<(DDIM * EDIM / 4 + 255) / 256, 256, 0, stream>>>(
        o_w, ow_bf, DDIM * EDIM / 4);

    rms_kernel<<<rows, 256, 0, stream>>>(x, ln_g, xn);
    gemm_bt3<0><<<dim3(FPAD / 256, rows / 256), 512, 0, stream>>>(
        xn, uvw_bf, FPAD, DDIM, uv, nullptr, 0, 0, 0, 0, 0);
    qk_kernel<<<rows, SATT, 0, stream>>>(uv, pos_enc, gamma, beta, qb, kb, FPAD);
    transpose_v<<<dim3(EDIM / 32, SEQ / 32, NBATCH), dim3(32, 8), 0, stream>>>(uv, vt, FPAD);
    gemm_bt3<1><<<dim3(SEQ / 256, SEQ / 256, NBATCH), 512, 0, stream>>>(
        qb, kb, SEQ, SATT, pmat, nullptr, 0,
        (size_t)SEQ * SATT, (size_t)SEQ * SATT, sP, 0);
    gemm_bt3<2><<<dim3(EDIM / 256, SEQ / 256, NBATCH), 512, 0, stream>>>(
        pmat, vt, EDIM, SEQ, z, uv, FPAD,
        sP, sVT, (size_t)SEQ * EDIM, (size_t)SEQ * FPAD);
    gemm_bt2<3><<<dim3(DDIM / 128, rows / 256), 512, 0, stream>>>(
        z, ow_bf, rows, DDIM, EDIM, nullptr, out, nullptr, 0,
        x, res_scale, 0, 0, 0, 0);
    return;
  }

  // ---------- fallback (small workspace): round-2 structure ----------
  u16* uvw_bf = (u16*)alloc((size_t)FDIM * DDIM * 2);
  u16* ow_bf  = (u16*)alloc(SZ_OW);
  u16* z      = (u16*)alloc(SZ_Z);
  u16* vt     = (u16*)alloc(SZ_VT1);
  u16* pmat   = (u16*)alloc(SZ_P1);
  size_t fixed = (size_t)(p - (char*)d_ws);
  const size_t perbc = (size_t)SEQ * DDIM * 2 + (size_t)SEQ * FDIM * 2 +
                       2 * (size_t)SEQ * SATT * 2 + 4 * 256;
  int BC = (ws_size >= fixed + 4 * perbc) ? 4 : 1;
  u16* xn = (u16*)alloc((size_t)BC * SEQ * DDIM * 2);
  u16* uv = (u16*)alloc((size_t)BC * SEQ * FDIM * 2);
  u16* qb = (u16*)alloc((size_t)BC * SEQ * SATT * 2);
  u16* kb = (u16*)alloc((size_t)BC * SEQ * SATT * 2);

  cvt_bf16_kernel<<<(FDIM * DDIM / 4 + 255) / 256, 256, 0, stream>>>(
      uv_w, uvw_bf, FDIM * DDIM / 4);
  cvt_bf16_kernel<<<(DDIM * EDIM / 4 + 255) / 256, 256, 0, stream>>>(
      o_w, ow_bf, DDIM * EDIM / 4);

  for (int b0 = 0; b0 < NBATCH; b0 += BC) {
    int rows = BC * SEQ;
    rms_kernel<<<rows, 256, 0, stream>>>(x + (size_t)b0 * SEQ * DDIM, ln_g, xn);
    gemm_bt<0><<<dim3(FDIM / 128, rows / 128), 256, 0, stream>>>(
        xn, uvw_bf, rows, FDIM, DDIM, uv, nullptr, nullptr, 0, nullptr, nullptr,
        0, 0, 0, 0);
    qk_kernel<<<rows, SATT, 0, stream>>>(uv, pos_enc, gamma, beta, qb, kb, FDIM);
    for (int bb = 0; bb < BC; bb++) {
      int b = b0 + bb;
      const u16* uvb = uv + (size_t)bb * SEQ * FDIM;
      transpose_v<<<dim3(EDIM / 32, SEQ / 32, 1), dim3(32, 8), 0, stream>>>(uvb, vt, FDIM);
      gemm_bt<1><<<dim3(SEQ / 128, SEQ / 128), 256, 0, stream>>>(
          qb + (size_t)bb * SEQ * SATT, kb + (size_t)bb * SEQ * SATT,
          SEQ, SEQ, SATT, pmat, nullptr, nullptr, 0, nullptr, nullptr,
          0, 0, 0, 0);
      gemm_bt<2><<<dim3(EDIM / 128, SEQ / 128), 256, 0, stream>>>(
          pmat, vt, SEQ, EDIM, SEQ, z + (size_t)b * SEQ * EDIM, nullptr,
          uvb, FDIM, nullptr, nullptr, 0, 0, 0, 0);
    }
  }
  gemm_bt<3><<<dim3(DDIM / 128, (NBATCH * SEQ) / 128), 256, 0, stream>>>(
      z, ow_bf, NBATCH * SEQ, DDIM, EDIM, nullptr, out, nullptr, 0,
      x, res_scale, 0, 0, 0, 0);
}

// Round 7
// 280.427 us; speedup vs baseline: 1.5422x; 1.0558x over previous
//
#include <hip/hip_runtime.h>

typedef unsigned short u16;
typedef __bf16 bf16x8 __attribute__((ext_vector_type(8)));
typedef float f32x4 __attribute__((ext_vector_type(4)));

#define SEQ   2048
#define DDIM  1024
#define EDIM  2048
#define FDIM  4224   /* 2E + S_ATT */
#define SATT  128
#define NBATCH 4

__device__ __forceinline__ u16 f2bf(float f) {
  unsigned u = __float_as_uint(f);
  unsigned r = (u + 0x7fffu + ((u >> 16) & 1u)) >> 16;
  return (u16)r;
}
__device__ __forceinline__ float bf2f(u16 v) {
  return __uint_as_float(((unsigned)v) << 16);
}

__device__ __forceinline__ void gload16(const u16* g, u16* l) {
  auto gp = (const __attribute__((address_space(1))) u16*)(unsigned long long)g;
  auto lp = (__attribute__((address_space(3))) u16*)(unsigned)(unsigned long long)l;
  __builtin_amdgcn_global_load_lds(gp, lp, 16, 0, 0);
}

// ---------------- elementwise / small kernels ----------------

__global__ void cvt_bf16_kernel(const float* __restrict__ in, u16* __restrict__ out, int n4) {
  int i = blockIdx.x * blockDim.x + threadIdx.x;
  if (i >= n4) return;
  float4 v = reinterpret_cast<const float4*>(in)[i];
  unsigned p0 = (unsigned)f2bf(v.x) | ((unsigned)f2bf(v.y) << 16);
  unsigned p1 = (unsigned)f2bf(v.z) | ((unsigned)f2bf(v.w) << 16);
  uint2 pk; pk.x = p0; pk.y = p1;
  reinterpret_cast<uint2*>(out)[i] = pk;
}

__global__ void rms_kernel(const float* __restrict__ x, const float* __restrict__ ln_g,
                           u16* __restrict__ xn) {
  int row = blockIdx.x;
  int t = threadIdx.x;
  const float4* xr = reinterpret_cast<const float4*>(x + (size_t)row * DDIM);
  float4 v = xr[t];
  float s = v.x * v.x + v.y * v.y + v.z * v.z + v.w * v.w;
#pragma unroll
  for (int off = 32; off > 0; off >>= 1) s += __shfl_down(s, off);
  __shared__ float wsum[4];
  int lane = t & 63, wv = t >> 6;
  if (lane == 0) wsum[wv] = s;
  __syncthreads();
  float tot = wsum[0] + wsum[1] + wsum[2] + wsum[3];
  float rms = sqrtf(tot * (1.0f / (float)DDIM));
  float scale = ln_g[0] / fmaxf(rms, 1e-5f);
  unsigned p0 = (unsigned)f2bf(v.x * scale) | ((unsigned)f2bf(v.y * scale) << 16);
  unsigned p1 = (unsigned)f2bf(v.z * scale) | ((unsigned)f2bf(v.w * scale) << 16);
  uint2 pk; pk.x = p0; pk.y = p1;
  reinterpret_cast<uint2*>(xn + (size_t)row * DDIM)[t] = pk;
}

__global__ void qk_kernel(const u16* __restrict__ uv, const float* __restrict__ pos_enc,
                          const float* __restrict__ gamma, const float* __restrict__ beta,
                          u16* __restrict__ q, u16* __restrict__ k, int ldF) {
  int r = blockIdx.x;
  int t = threadIdx.x;
  int s = r & (SEQ - 1);
  float bval = bf2f(uv[(size_t)r * ldF + 2 * EDIM + t]);
  float pe = pos_enc[(size_t)s * SATT + t];
  float qv = bval * gamma[t] + beta[t] + pe;
  float kv = bval * gamma[SATT + t] + beta[SATT + t] + pe;
  q[(size_t)r * SATT + t] = f2bf(qv);
  k[(size_t)r * SATT + t] = f2bf(kv);
}

// vt[b][e][s] = uv[b][s][E + e]
__global__ void transpose_v(const u16* __restrict__ uv, u16* __restrict__ vt, int ldF) {
  __shared__ u16 tile[32][33];
  int b = blockIdx.z;
  uv += (size_t)b * SEQ * ldF;
  vt += (size_t)b * EDIM * SEQ;
  int e0 = blockIdx.x * 32, s0 = blockIdx.y * 32;
  int tx = threadIdx.x, ty = threadIdx.y;
#pragma unroll
  for (int j = 0; j < 32; j += 8)
    tile[ty + j][tx] = uv[(size_t)(s0 + ty + j) * ldF + EDIM + e0 + tx];
  __syncthreads();
#pragma unroll
  for (int j = 0; j < 32; j += 8)
    vt[(size_t)(e0 + ty + j) * SEQ + s0 + tx] = tile[tx][ty + j];
}

// ======== quadrant-phase GEMM v3: C = A(M,K)*B(N,K)^T ========
// BM=BN=256 (last col-tile may be ragged 128-wide), BK=64, 512 thr = 8 waves
// (2 wm x 4 wn), per-wave 128x64. LDS 128 KiB = 2 dbuf x 4 panels of 16 KiB.
// K-loop unrolled x2 (buf compile-time); ds_read addresses = 8 precomputed
// swizzled base pointers + immediate (XOR bits 4-6 are lane-constant since
// row&7 == lane&7 and s*64+kg*16 occupy exactly bits 4-6).
// Stages for tile t+2 -> current buf, after each panel's last read.
// One counted vmcnt(6) per tile at the ph3 boundary.
template <int EPI>
__global__ __launch_bounds__(512, 2) void gemm_bt3(
    const u16* __restrict__ A, const u16* __restrict__ B,
    int N, int K,
    u16* __restrict__ Cbf,
    const u16* __restrict__ U, int ldu,
    size_t sA, size_t sB, size_t sC, size_t sU) {
  __shared__ u16 lds[65536];  // 128 KiB
  const int tid = threadIdx.x;
  const int w = tid >> 6, l = tid & 63;
  const int wm2 = w >> 2, wn2 = w & 3;
  const int fr = l & 15, kg = l >> 4;

  const int bz = blockIdx.z;
  A += (size_t)bz * sA; B += (size_t)bz * sB; U += (size_t)bz * sU;

  // XCD-aware bijective swizzle (nwg % 8 == 0 for all launched shapes)
  const int nbx = gridDim.x;
  int li = blockIdx.y * nbx + blockIdx.x;
  const int cpx = (nbx * gridDim.y) >> 3;
  li = (li & 7) * cpx + (li >> 3);
  const int bn = li % nbx;
  const int bm = li / nbx;

  const int NT = K >> 6;                     // even for all callers
  const bool full = (bn * 256 + 256 <= N);   // block-uniform ragged flag

  const int r0 = (w << 3) + (l >> 3);                  // staging row 0..63
  const int cswz = (((l & 7) ^ (l >> 3)) & 7) << 3;    // inv-swizzled col

  // staging pointers: 4 panels x 2 row-groups; advance 128 elems / 2 tiles
  const u16* pA00 = A + (size_t)bm * 256 * K + (size_t)r0 * K + cswz;
  const u16* pA01 = pA00 + (size_t)64 * K;
  const u16* pA10 = pA00 + (size_t)128 * K;
  const u16* pA11 = pA00 + (size_t)192 * K;
  const u16* pB00 = B + (size_t)bn * 256 * K + (size_t)r0 * K + cswz;
  const u16* pB01 = pB00 + (size_t)64 * K;
  const u16* pB10 = pB00 + (size_t)128 * K;
  const u16* pB11 = pB00 + (size_t)192 * K;

  // precomputed swizzled LDS read bases
  const int X  = (l & 7) << 4;
  const int Y0 = (kg << 4) ^ X;
  const int Y1 = ((kg << 4) | 64) ^ X;
  const char* ldsC = (const char*)lds;
  const char* aR[2][2];
  const char* bR[2][2];
  aR[0][0] = ldsC + wm2 * 8192 + fr * 128 + Y0;
  aR[0][1] = ldsC + wm2 * 8192 + fr * 128 + Y1;
  aR[1][0] = aR[0][0] + 65536;
  aR[1][1] = aR[0][1] + 65536;
  bR[0][0] = ldsC + 32768 + wn2 * 4096 + fr * 128 + Y0;
  bR[0][1] = ldsC + 32768 + wn2 * 4096 + fr * 128 + Y1;
  bR[1][0] = bR[0][0] + 65536;
  bR[1][1] = bR[0][1] + 65536;

  // LDS stage destination: word off = buf*32768 + p*8192 + w*512 (+4096 L1)
  auto stg = [&](int bufw, int p, const u16* g0, const u16* g1, int ofs) {
    u16* d = lds + bufw * 32768 + p * 8192 + w * 512;
    gload16(g0 + ofs, d);
    gload16(g1 + ofs, d + 4096);
  };

  f32x4 acc[8][4];
#pragma unroll
  for (int i = 0; i < 8; i++)
#pragma unroll
    for (int j = 0; j < 4; j++) acc[i][j] = f32x4{0.f, 0.f, 0.f, 0.f};

  // prologue: stage tiles 0 (buf0) and 1 (buf1)
  stg(0, 0, pA00, pA01, 0); stg(0, 2, pB00, pB01, 0);
  if (full) stg(0, 3, pB10, pB11, 0);
  stg(0, 1, pA10, pA11, 0);
  if (NT > 1) {
    stg(1, 0, pA00, pA01, 64); stg(1, 2, pB00, pB01, 64);
    if (full) stg(1, 3, pB10, pB11, 64);
    stg(1, 1, pA10, pA11, 64);
    if (full) asm volatile("s_waitcnt vmcnt(8)" ::: "memory");
    else      asm volatile("s_waitcnt vmcnt(6)" ::: "memory");
  } else {
    asm volatile("s_waitcnt vmcnt(0)" ::: "memory");
  }
  __builtin_amdgcn_s_barrier();

  bf16x8 aH[4][2], bF[2][2][2];  // bF[qb][j][s]

#define MFMA_Q(QA, QB)                                                        \
  _Pragma("unroll") for (int s = 0; s < 2; s++)                               \
  _Pragma("unroll") for (int i = 0; i < 4; i++)                               \
  _Pragma("unroll") for (int j = 0; j < 2; j++)                               \
    acc[(QA)*4 + i][(QB)*2 + j] = __builtin_amdgcn_mfma_f32_16x16x32_bf16(    \
        aH[i][s], bF[QB][j][s], acc[(QA)*4 + i][(QB)*2 + j], 0, 0, 0);

#define TILE_STEP(BUF, ST, OFS)                                               \
  {                                                                           \
    /* ph0: read A-h0(8)+B-h0(4); MFMA q(0,0) */                              \
    _Pragma("unroll") for (int i = 0; i < 4; i++)                             \
    _Pragma("unroll") for (int s = 0; s < 2; s++)                             \
      aH[i][s] = *(const bf16x8*)(aR[BUF][s] + i * 2048);                     \
    _Pragma("unroll") for (int j = 0; j < 2; j++)                             \
    _Pragma("unroll") for (int s = 0; s < 2; s++)                             \
      bF[0][j][s] = *(const bf16x8*)(bR[BUF][s] + j * 2048);                  \
    asm volatile("s_waitcnt lgkmcnt(8)" ::: "memory");                        \
    __builtin_amdgcn_s_barrier();                                             \
    asm volatile("s_waitcnt lgkmcnt(0)" ::: "memory");                        \
    __builtin_amdgcn_s_setprio(1);                                            \
    MFMA_Q(0, 0)                                                              \
    __builtin_amdgcn_s_setprio(0);                                            \
    __builtin_amdgcn_s_barrier();                                             \
    /* ph1: read B-h1(4); stage (t+2).A-h0,B-h0; MFMA q(0,1) */               \
    if (full) {                                                               \
      _Pragma("unroll") for (int j = 0; j < 2; j++)                           \
      _Pragma("unroll") for (int s = 0; s < 2; s++)                           \
        bF[1][j][s] = *(const bf16x8*)(bR[BUF][s] + 16384 + j * 2048);        \
    }                                                                         \
    if (ST) { stg(BUF, 0, pA00, pA01, OFS); stg(BUF, 2, pB00, pB01, OFS); }   \
    __builtin_amdgcn_s_barrier();                                             \
    asm volatile("s_waitcnt lgkmcnt(0)" ::: "memory");                        \
    __builtin_amdgcn_s_setprio(1);                                            \
    if (full) { MFMA_Q(0, 1) }                                                \
    __builtin_amdgcn_s_setprio(0);                                            \
    __builtin_amdgcn_s_barrier();                                             \
    /* ph2: read A-h1(8); stage (t+2).B-h1; MFMA q(1,0) */                    \
    _Pragma("unroll") for (int i = 0; i < 4; i++)                             \
    _Pragma("unroll") for (int s = 0; s < 2; s++)                             \
      aH[i][s] = *(const bf16x8*)(aR[BUF][s] + 16384 + i * 2048);             \
    if ((ST) && full) { stg(BUF, 3, pB10, pB11, OFS); }                       \
    __builtin_amdgcn_s_barrier();                                             \
    asm volatile("s_waitcnt lgkmcnt(0)" ::: "memory");                        \
    __builtin_amdgcn_s_setprio(1);                                            \
    MFMA_Q(1, 0)                                                              \
    __builtin_amdgcn_s_setprio(0);                                            \
    __builtin_amdgcn_s_barrier();                                             \
    /* ph3: stage (t+2).A-h1; MFMA q(1,1); boundary vmcnt */                  \
    if (ST) { stg(BUF, 1, pA10, pA11, OFS); }                                 \
    __builtin_amdgcn_s_setprio(1);                                            \
    if (full) { MFMA_Q(1, 1) }                                                \
    __builtin_amdgcn_s_setprio(0);                                            \
    if (ST) asm volatile("s_waitcnt vmcnt(6)" ::: "memory");                  \
    else    asm volatile("s_waitcnt vmcnt(0)" ::: "memory");                  \
    __builtin_amdgcn_s_barrier();                                             \
  }

  for (int t2 = 0; t2 < NT; t2 += 2) {
    const bool st0 = (t2 + 2 < NT);
    const bool st1 = (t2 + 3 < NT);
    TILE_STEP(0, st0, 128)
    TILE_STEP(1, st1, 192)
    pA00 += 128; pA01 += 128; pA10 += 128; pA11 += 128;
    pB00 += 128; pB01 += 128; pB10 += 128; pB11 += 128;
  }
#undef TILE_STEP
#undef MFMA_Q

  // epilogue
  const int rsub = (l >> 4) * 4;
  const int ccol = l & 15;
#pragma unroll
  for (int ai = 0; ai < 8; ai++) {
#pragma unroll
    for (int bj = 0; bj < 4; bj++) {
      if (!full && bj >= 2) continue;
      int n = bn * 256 + (bj >> 1) * 128 + wn2 * 32 + (bj & 1) * 16 + ccol;
#pragma unroll
      for (int tt = 0; tt < 4; tt++) {
        int m = bm * 256 + (ai >> 2) * 128 + wm2 * 64 + (ai & 3) * 16 + rsub + tt;
        float v = acc[ai][bj][tt];
        size_t idx = (size_t)m * N + n;
        if constexpr (EPI == 0) {
          float sv = v / (1.f + __expf(-v));
          Cbf[(size_t)bz * sC + idx] = f2bf(sv);
        } else if constexpr (EPI == 1) {
          float sc = v * 0.08838834764831845f;  // 1/sqrt(128)
          sc = sc > 0.f ? sc * sc : 0.f;
          Cbf[(size_t)bz * sC + idx] = f2bf(sc);
        } else {
          float uvl = bf2f(U[(size_t)m * ldu + n]);
          Cbf[(size_t)bz * sC + idx] = f2bf(v * uvl);
        }
      }
    }
  }
}

// ======== 256x128 deep-pipeline GEMM (gemm3; round-3 proven) ====
template <int EPI>
__global__ __launch_bounds__(512, 2) void gemm_bt2(
    const u16* __restrict__ A, const u16* __restrict__ B,
    int M, int N, int K,
    u16* __restrict__ Cbf, float* __restrict__ Cf,
    const u16* __restrict__ U, int ldu,
    const float* __restrict__ Xres, const float* __restrict__ rscale,
    size_t sA, size_t sB, size_t sC, size_t sU) {
  __shared__ u16 lds[3 * 24576];  // 144 KiB
  const int tid = threadIdx.x;
  const int w = tid >> 6, l = tid & 63;
  const int wr = w >> 1, wc = w & 1;
  const int fr = l & 15, kg = l >> 4;

  const int bz = blockIdx.z;
  A += (size_t)bz * sA; B += (size_t)bz * sB; U += (size_t)bz * sU;

  const int nbx = gridDim.x;
  int li = blockIdx.y * nbx + blockIdx.x;
  const int cpx = (nbx * gridDim.y) >> 3;
  li = (li & 7) * cpx + (li >> 3);
  const int bn = li % nbx;
  const int bm = li / nbx;

  const int NT = K >> 6;
  const int srow = (w << 3) + (l >> 3);
  const int scol = (((l & 7) ^ (l >> 3)) & 7) << 3;
  const size_t aoff = (size_t)bm * 256 * K;
  const size_t boff = (size_t)bn * 128 * K;
  const char* ldsC = (const char*)lds;

  auto stageAu = [&](int t, int h) {
    int sb = (t % 3) * 24576 + h * 8192;
    const u16* g = A + aoff + (size_t)(h * 128 + srow) * K + t * 64 + scol;
#pragma unroll
    for (int L = 0; L < 2; L++)
      gload16(g + (size_t)(L * 64) * K, &lds[sb + (L * 8 + w) * 512]);
  };
  auto stageBu = [&](int t) {
    int sb = (t % 3) * 24576 + 16384;
    const u16* g = B + boff + (size_t)srow * K + t * 64 + scol;
#pragma unroll
    for (int L = 0; L < 2; L++)
      gload16(g + (size_t)(L * 64) * K, &lds[sb + (L * 8 + w) * 512]);
  };
  auto ldA = [&](int cur, int i, int s) -> bf16x8 {
    int r = ((wr & 1) << 6) + (i << 4) + fr;
    int off = cur * 49152 + ((wr >> 1) << 14) + (r << 7) + (s << 6) + (kg << 4);
    off ^= (r & 7) << 4;
    return *(const bf16x8*)(ldsC + off);
  };
  auto ldB = [&](int cur, int j, int s) -> bf16x8 {
    int r = (wc << 6) + (j << 4) + fr;
    int off = cur * 49152 + 32768 + (r << 7) + (s << 6) + (kg << 4);
    off ^= (r & 7) << 4;
    return *(const bf16x8*)(ldsC + off);
  };

  f32x4 acc[4][4];
#pragma unroll
  for (int i = 0; i < 4; i++)
#pragma unroll
    for (int j = 0; j < 4; j++) acc[i][j] = f32x4{0.f, 0.f, 0.f, 0.f};

  stageAu(0, 0); stageAu(0, 1); stageBu(0);
  if (NT > 1) { stageAu(1, 0); stageAu(1, 1); stageBu(1); }
  asm volatile("s_waitcnt vmcnt(6)" ::: "memory");
  __builtin_amdgcn_s_barrier();

  bf16x8 aF[2][2], bF[2][2][2];
  for (int t = 0; t < NT; ++t) {
    const int cur = t % 3;
    const bool st = (t + 2 < NT);
#pragma unroll
    for (int i = 0; i < 2; i++)
#pragma unroll
      for (int s = 0; s < 2; s++) aF[i][s] = ldA(cur, i, s);
#pragma unroll
    for (int j = 0; j < 2; j++)
#pragma unroll
      for (int s = 0; s < 2; s++) bF[0][j][s] = ldB(cur, j, s);
    if (st) stageAu(t + 2, 0);
    __builtin_amdgcn_s_barrier();
    __builtin_amdgcn_s_setprio(1);
#pragma unroll
    for (int s = 0; s < 2; s++)
#pragma unroll
      for (int i = 0; i < 2; i++)
#pragma unroll
        for (int j = 0; j < 2; j++)
          acc[i][j] = __builtin_amdgcn_mfma_f32_16x16x32_bf16(aF[i][s], bF[0][j][s], acc[i][j], 0, 0, 0);
    __builtin_amdgcn_s_setprio(0);
    __builtin_amdgcn_s_barrier();
#pragma unroll
    for (int j = 0; j < 2; j++)
#pragma unroll
      for (int s = 0; s < 2; s++) bF[1][j][s] = ldB(cur, 2 + j, s);
    if (st) stageAu(t + 2, 1);
    __builtin_amdgcn_s_barrier();
    __builtin_amdgcn_s_setprio(1);
#pragma unroll
    for (int s = 0; s < 2; s++)
#pragma unroll
      for (int i = 0; i < 2; i++)
#pragma unroll
        for (int j = 0; j < 2; j++)
          acc[i][2 + j] = __builtin_amdgcn_mfma_f32_16x16x32_bf16(aF[i][s], bF[1][j][s], acc[i][2 + j], 0, 0, 0);
    __builtin_amdgcn_s_setprio(0);
    __builtin_amdgcn_s_barrier();
#pragma unroll
    for (int i = 0; i < 2; i++)
#pragma unroll
      for (int s = 0; s < 2; s++) aF[i][s] = ldA(cur, 2 + i, s);
    if (st) stageBu(t + 2);
    __builtin_amdgcn_s_barrier();
    __builtin_amdgcn_s_setprio(1);
#pragma unroll
    for (int s = 0; s < 2; s++)
#pragma unroll
      for (int i = 0; i < 2; i++)
#pragma unroll
        for (int j = 0; j < 2; j++)
          acc[2 + i][j] = __builtin_amdgcn_mfma_f32_16x16x32_bf16(aF[i][s], bF[0][j][s], acc[2 + i][j], 0, 0, 0);
    __builtin_amdgcn_s_setprio(0);
    __builtin_amdgcn_s_barrier();
    __builtin_amdgcn_s_setprio(1);
#pragma unroll
    for (int s = 0; s < 2; s++)
#pragma unroll
      for (int i = 0; i < 2; i++)
#pragma unroll
        for (int j = 0; j < 2; j++)
          acc[2 + i][2 + j] = __builtin_amdgcn_mfma_f32_16x16x32_bf16(aF[i][s], bF[1][j][s], acc[2 + i][2 + j], 0, 0, 0);
    __builtin_amdgcn_s_setprio(0);
    if (st) asm volatile("s_waitcnt vmcnt(6)" ::: "memory");
    else    asm volatile("s_waitcnt vmcnt(0)" ::: "memory");
    __builtin_amdgcn_s_barrier();
  }

  const int m0 = bm * 256 + wr * 64;
  const int n0 = bn * 128 + wc * 64;
  const int rsub = (l >> 4) * 4;
  const int ccol = l & 15;
#pragma unroll
  for (int i = 0; i < 4; i++) {
#pragma unroll
    for (int j = 0; j < 4; j++) {
      int n = n0 + j * 16 + ccol;
#pragma unroll
      for (int tt = 0; tt < 4; tt++) {
        int m = m0 + i * 16 + rsub + tt;
        float v = acc[i][j][tt];
        size_t idx = (size_t)m * N + n;
        if constexpr (EPI == 0) {
          float sv = v / (1.f + __expf(-v));
          Cbf[(size_t)bz * sC + idx] = f2bf(sv);
        } else if constexpr (EPI == 1) {
          float sc = v * 0.08838834764831845f;
          sc = sc > 0.f ? sc * sc : 0.f;
          Cbf[(size_t)bz * sC + idx] = f2bf(sc);
        } else if constexpr (EPI == 2) {
          float uvl = bf2f(U[(size_t)m * ldu + n]);
          Cbf[(size_t)bz * sC + idx] = f2bf(v * uvl);
        } else {
          Cf[idx] = Xres[idx] * rscale[n] + v;
        }
      }
    }
  }
}

// ---------------- legacy 128x128 GEMM (fallback path only) ----------------
template <int EPI>
__global__ __launch_bounds__(256) void gemm_bt(
    const u16* __restrict__ A, const u16* __restrict__ B,
    int M, int N, int K,
    u16* __restrict__ Cbf, float* __restrict__ Cf,
    const u16* __restrict__ U, int ldu,
    const float* __restrict__ Xres, const float* __restrict__ rscale,
    size_t sA, size_t sB, size_t sC, size_t sU) {
  __shared__ u16 As[128 * 32];
  __shared__ u16 Bs[128 * 32];
  const int tid = threadIdx.x;
  const int wave = tid >> 6, lane = tid & 63;
  const int wr = wave >> 1, wc = wave & 1;
  const int bz = blockIdx.z;
  A += (size_t)bz * sA; B += (size_t)bz * sB; U += (size_t)bz * sU;
  const int nbx = gridDim.x;
  int li = blockIdx.y * nbx + blockIdx.x;
  const int cpx = (nbx * gridDim.y) >> 3;
  li = (li & 7) * cpx + (li >> 3);
  const int bn = li % nbx;
  const int bm = li / nbx;
  const size_t abase = (size_t)bm * 128 * K;
  const size_t bbase = (size_t)bn * 128 * K;
  const int srow = tid >> 2;
  const int scol = (tid & 3) * 8;
  f32x4 acc[4][4];
#pragma unroll
  for (int i = 0; i < 4; i++)
#pragma unroll
    for (int j = 0; j < 4; j++) acc[i][j] = f32x4{0.f, 0.f, 0.f, 0.f};
  const int fr = lane & 15;
  const int fk = (lane >> 4) * 8;
  for (int k0 = 0; k0 < K; k0 += 32) {
#pragma unroll
    for (int r = 0; r < 2; r++) {
      const u16* gA = A + abase + (size_t)(r * 64 + srow) * K + k0 + scol;
      const u16* gB = B + bbase + (size_t)(r * 64 + srow) * K + k0 + scol;
      gload16(gA, As + r * 2048 + wave * 512);
      gload16(gB, Bs + r * 2048 + wave * 512);
    }
    __syncthreads();
    bf16x8 af[4], bfr[4];
#pragma unroll
    for (int i = 0; i < 4; i++) {
      af[i]  = *reinterpret_cast<const bf16x8*>(&As[(wr * 64 + i * 16 + fr) * 32 + fk]);
      bfr[i] = *reinterpret_cast<const bf16x8*>(&Bs[(wc * 64 + i * 16 + fr) * 32 + fk]);
    }
#pragma unroll
    for (int i = 0; i < 4; i++)
#pragma unroll
      for (int j = 0; j < 4; j++)
        acc[i][j] = __builtin_amdgcn_mfma_f32_16x16x32_bf16(af[i], bfr[j], acc[i][j], 0, 0, 0);
    __syncthreads();
  }
  const int m0 = bm * 128 + wr * 64;
  const int n0 = bn * 128 + wc * 64;
  const int rsub = (lane >> 4) * 4;
  const int ccol = lane & 15;
#pragma unroll
  for (int i = 0; i < 4; i++) {
#pragma unroll
    for (int j = 0; j < 4; j++) {
      int n = n0 + j * 16 + ccol;
#pragma unroll
      for (int t = 0; t < 4; t++) {
        int m = m0 + i * 16 + rsub + t;
        float v = acc[i][j][t];
        size_t idx = (size_t)m * N + n;
        if constexpr (EPI == 0) {
          float sv = v / (1.f + __expf(-v));
          Cbf[(size_t)bz * sC + idx] = f2bf(sv);
        } else if constexpr (EPI == 1) {
          float sc = v * 0.08838834764831845f;
          sc = sc > 0.f ? sc * sc : 0.f;
          Cbf[(size_t)bz * sC + idx] = f2bf(sc);
        } else if constexpr (EPI == 2) {
          float uvl = bf2f(U[(size_t)m * ldu + n]);
          Cbf[(size_t)bz * sC + idx] = f2bf(v * uvl);
        } else {
          Cf[idx] = Xres[idx] * rscale[n] + v;
        }
      }
    }
  }
}

// ---------------- launcher ----------------

extern "C" void kernel_launch(void* const* d_in, const int* in_sizes, int n_in,
                              void* d_out, int out_size, void* d_ws, size_t ws_size,
                              hipStream_t stream) {
  const float* x        = (const float*)d_in[0];
  const float* pos_enc  = (const float*)d_in[1];
  const float* uv_w     = (const float*)d_in[2];
  const float* o_w      = (const float*)d_in[3];
  const float* gamma    = (const float*)d_in[4];
  const float* beta     = (const float*)d_in[5];
  const float* ln_g     = (const float*)d_in[6];
  const float* res_scale= (const float*)d_in[7];
  float* out = (float*)d_out;

  auto al = [](size_t b) { return (b + 255) & ~(size_t)255; };
  const size_t SZ_UVW  = (size_t)FDIM * DDIM * 2;
  const size_t SZ_OW   = (size_t)DDIM * EDIM * 2;
  const size_t SZ_Z    = (size_t)NBATCH * SEQ * EDIM * 2;
  const size_t SZ_XN   = (size_t)NBATCH * SEQ * DDIM * 2;
  const size_t SZ_UV   = (size_t)NBATCH * SEQ * FDIM * 2;
  const size_t SZ_QK   = (size_t)NBATCH * SEQ * SATT * 2;
  const size_t SZ_VT1  = (size_t)EDIM * SEQ * 2;
  const size_t SZ_P1   = (size_t)SEQ * SEQ * 2;
  const size_t need_full =
      al(SZ_UVW) + al(SZ_OW) + al(SZ_Z) + al(SZ_XN) + al(SZ_UV) + 2 * al(SZ_QK) +
      (size_t)NBATCH * (al(SZ_VT1) + al(SZ_P1));
  const bool FULL = ws_size >= need_full;

  char* p = (char*)d_ws;
  auto alloc = [&](size_t bytes) {
    char* r = p;
    p += (bytes + 255) & ~(size_t)255;
    return r;
  };

  if (FULL) {
    u16* uvw_bf = (u16*)alloc(SZ_UVW);
    u16* ow_bf  = (u16*)alloc(SZ_OW);
    u16* z      = (u16*)alloc(SZ_Z);
    u16* vt     = (u16*)alloc((size_t)NBATCH * al(SZ_VT1));
    u16* pmat   = (u16*)alloc((size_t)NBATCH * al(SZ_P1));
    u16* xn     = (u16*)alloc(SZ_XN);
    u16* uv     = (u16*)alloc(SZ_UV);
    u16* qb     = (u16*)alloc(SZ_QK);
    u16* kb     = (u16*)alloc(SZ_QK);
    const size_t sVT = al(SZ_VT1) >> 1;
    const size_t sP  = al(SZ_P1) >> 1;
    const int rows = NBATCH * SEQ;  // 8192

    cvt_bf16_kernel<<<(FDIM * DDIM / 4 + 255) / 256, 256, 0, stream>>>(
        uv_w, uvw_bf, FDIM * DDIM / 4);
    cvt_bf16_kernel<<<(DDIM * EDIM / 4 + 255) / 256, 256, 0, stream>>>(
        o_w, ow_bf, DDIM * EDIM / 4);

    rms_kernel<<<rows, 256, 0, stream>>>(x, ln_g, xn);
    // gemm0: 17 col-tiles, last one ragged (128 wide) -> 544 blocks, 512 full
    gemm_bt3<0><<<dim3(17, rows / 256), 512, 0, stream>>>(
        xn, uvw_bf, FDIM, DDIM, uv, nullptr, 0, 0, 0, 0, 0);
    qk_kernel<<<rows, SATT, 0, stream>>>(uv, pos_enc, gamma, beta, qb, kb, FDIM);
    transpose_v<<<dim3(EDIM / 32, SEQ / 32, NBATCH), dim3(32, 8), 0, stream>>>(uv, vt, FDIM);
    gemm_bt3<1><<<dim3(SEQ / 256, SEQ / 256, NBATCH), 512, 0, stream>>>(
        qb, kb, SEQ, SATT, pmat, nullptr, 0,
        (size_t)SEQ * SATT, (size_t)SEQ * SATT, sP, 0);
    gemm_bt3<2><<<dim3(EDIM / 256, SEQ / 256, NBATCH), 512, 0, stream>>>(
        pmat, vt, EDIM, SEQ, z, uv, FDIM,
        sP, sVT, (size_t)SEQ * EDIM, (size_t)SEQ * FDIM);
    gemm_bt2<3><<<dim3(DDIM / 128, rows / 256), 512, 0, stream>>>(
        z, ow_bf, rows, DDIM, EDIM, nullptr, out, nullptr, 0,
        x, res_scale, 0, 0, 0, 0);
    return;
  }

  // ---------- fallback (small workspace): round-2 structure ----------
  u16* uvw_bf = (u16*)alloc(SZ_UVW);
  u16* ow_bf  = (u16*)alloc(SZ_OW);
  u16* z      = (u16*)alloc(SZ_Z);
  u16* vt     = (u16*)alloc(SZ_VT1);
  u16* pmat   = (u16*)alloc(SZ_P1);
  size_t fixed = (size_t)(p - (char*)d_ws);
  const size_t perbc = (size_t)SEQ * DDIM * 2 + (size_t)SEQ * FDIM * 2 +
                       2 * (size_t)SEQ * SATT * 2 + 4 * 256;
  int BC = (ws_size >= fixed + 4 * perbc) ? 4 : 1;
  u16* xn = (u16*)alloc((size_t)BC * SEQ * DDIM * 2);
  u16* uv = (u16*)alloc((size_t)BC * SEQ * FDIM * 2);
  u16* qb = (u16*)alloc((size_t)BC * SEQ * SATT * 2);
  u16* kb = (u16*)alloc((size_t)BC * SEQ * SATT * 2);

  cvt_bf16_kernel<<<(FDIM * DDIM / 4 + 255) / 256, 256, 0, stream>>>(
      uv_w, uvw_bf, FDIM * DDIM / 4);
  cvt_bf16_kernel<<<(DDIM * EDIM / 4 + 255) / 256, 256, 0, stream>>>(
      o_w, ow_bf, DDIM * EDIM / 4);

  for (int b0 = 0; b0 < NBATCH; b0 += BC) {
    int rows = BC * SEQ;
    rms_kernel<<<rows, 256, 0, stream>>>(x + (size_t)b0 * SEQ * DDIM, ln_g, xn);
    gemm_bt<0><<<dim3(FDIM / 128, rows / 128), 256, 0, stream>>>(
        xn, uvw_bf, rows, FDIM, DDIM, uv, nullptr, nullptr, 0, nullptr, nullptr,
        0, 0, 0, 0);
    qk_kernel<<<rows, SATT, 0, stream>>>(uv, pos_enc, gamma, beta, qb, kb, FDIM);
    for (int bb = 0; bb < BC; bb++) {
      int b = b0 + bb;
      const u16* uvb = uv + (size_t)bb * SEQ * FDIM;
      transpose_v<<<dim3(EDIM / 32, SEQ / 32, 1), dim3(32, 8), 0, stream>>>(uvb, vt, FDIM);
      gemm_bt<1><<<dim3(SEQ / 128, SEQ / 128), 256, 0, stream>>>(
          qb + (size_t)bb * SEQ * SATT, kb + (size_t)bb * SEQ * SATT,
          SEQ, SEQ, SATT, pmat, nullptr, nullptr, 0, nullptr, nullptr,
          0, 0, 0, 0);
      gemm_bt<2><<<dim3(EDIM / 128, SEQ / 128), 256, 0, stream>>>(
          pmat, vt, SEQ, EDIM, SEQ, z + (size_t)b * SEQ * EDIM, nullptr,
          uvb, FDIM, nullptr, nullptr, 0, 0, 0, 0);
    }
  }
  gemm_bt<3><<<dim3(DDIM / 128, (NBATCH * SEQ) / 128), 256, 0, stream>>>(
      z, ow_bf, NBATCH * SEQ, DDIM, EDIM, nullptr, out, nullptr, 0,
      x, res_scale, 0, 0, 0, 0);
}

// Round 8
// 273.322 us; speedup vs baseline: 1.5823x; 1.0260x over previous
//
#include <hip/hip_runtime.h>

typedef unsigned short u16;
typedef __bf16 bf16x8 __attribute__((ext_vector_type(8)));
typedef float f32x4 __attribute__((ext_vector_type(4)));

#define SEQ   2048
#define DDIM  1024
#define EDIM  2048
#define FDIM  4224   /* 2E + S_ATT */
#define SATT  128
#define NBATCH 4

__device__ __forceinline__ u16 f2bf(float f) {
  unsigned u = __float_as_uint(f);
  unsigned r = (u + 0x7fffu + ((u >> 16) & 1u)) >> 16;
  return (u16)r;
}
__device__ __forceinline__ float bf2f(u16 v) {
  return __uint_as_float(((unsigned)v) << 16);
}

__device__ __forceinline__ void gload16(const u16* g, u16* l) {
  auto gp = (const __attribute__((address_space(1))) u16*)(unsigned long long)g;
  auto lp = (__attribute__((address_space(3))) u16*)(unsigned)(unsigned long long)l;
  __builtin_amdgcn_global_load_lds(gp, lp, 16, 0, 0);
}

// ---------------- elementwise / small kernels ----------------

__global__ void cvt_bf16_kernel(const float* __restrict__ in, u16* __restrict__ out, int n4) {
  int i = blockIdx.x * blockDim.x + threadIdx.x;
  if (i >= n4) return;
  float4 v = reinterpret_cast<const float4*>(in)[i];
  unsigned p0 = (unsigned)f2bf(v.x) | ((unsigned)f2bf(v.y) << 16);
  unsigned p1 = (unsigned)f2bf(v.z) | ((unsigned)f2bf(v.w) << 16);
  uint2 pk; pk.x = p0; pk.y = p1;
  reinterpret_cast<uint2*>(out)[i] = pk;
}

__global__ void rms_kernel(const float* __restrict__ x, const float* __restrict__ ln_g,
                           u16* __restrict__ xn) {
  int row = blockIdx.x;
  int t = threadIdx.x;
  const float4* xr = reinterpret_cast<const float4*>(x + (size_t)row * DDIM);
  float4 v = xr[t];
  float s = v.x * v.x + v.y * v.y + v.z * v.z + v.w * v.w;
#pragma unroll
  for (int off = 32; off > 0; off >>= 1) s += __shfl_down(s, off);
  __shared__ float wsum[4];
  int lane = t & 63, wv = t >> 6;
  if (lane == 0) wsum[wv] = s;
  __syncthreads();
  float tot = wsum[0] + wsum[1] + wsum[2] + wsum[3];
  float rms = sqrtf(tot * (1.0f / (float)DDIM));
  float scale = ln_g[0] / fmaxf(rms, 1e-5f);
  unsigned p0 = (unsigned)f2bf(v.x * scale) | ((unsigned)f2bf(v.y * scale) << 16);
  unsigned p1 = (unsigned)f2bf(v.z * scale) | ((unsigned)f2bf(v.w * scale) << 16);
  uint2 pk; pk.x = p0; pk.y = p1;
  reinterpret_cast<uint2*>(xn + (size_t)row * DDIM)[t] = pk;
}

__global__ void qk_kernel(const u16* __restrict__ uv, const float* __restrict__ pos_enc,
                          const float* __restrict__ gamma, const float* __restrict__ beta,
                          u16* __restrict__ q, u16* __restrict__ k, int ldF) {
  int r = blockIdx.x;
  int t = threadIdx.x;
  int s = r & (SEQ - 1);
  float bval = bf2f(uv[(size_t)r * ldF + 2 * EDIM + t]);
  float pe = pos_enc[(size_t)s * SATT + t];
  float qv = bval * gamma[t] + beta[t] + pe;
  float kv = bval * gamma[SATT + t] + beta[SATT + t] + pe;
  q[(size_t)r * SATT + t] = f2bf(qv);
  k[(size_t)r * SATT + t] = f2bf(kv);
}

// vt[b][e][s] = uv[b][s][E + e]
__global__ void transpose_v(const u16* __restrict__ uv, u16* __restrict__ vt, int ldF) {
  __shared__ u16 tile[32][33];
  int b = blockIdx.z;
  uv += (size_t)b * SEQ * ldF;
  vt += (size_t)b * EDIM * SEQ;
  int e0 = blockIdx.x * 32, s0 = blockIdx.y * 32;
  int tx = threadIdx.x, ty = threadIdx.y;
#pragma unroll
  for (int j = 0; j < 32; j += 8)
    tile[ty + j][tx] = uv[(size_t)(s0 + ty + j) * ldF + EDIM + e0 + tx];
  __syncthreads();
#pragma unroll
  for (int j = 0; j < 32; j += 8)
    vt[(size_t)(e0 + ty + j) * SEQ + s0 + tx] = tile[tx][ty + j];
}

// ======== GEMM v4 (single-barrier tile, compiler-scheduled body) ========
// C = A(M,K)*B(N,K)^T. BM=BN=256 (last col-tile may be ragged 128), BK=64,
// 512 thr = 8 waves (2 wm x 4 wn), per-wave 128x64.
// LDS 128 KiB = 2 dbuf x 4 panels of 16 KiB. Classic double buffer:
// at tile t top, stage tile t+1 -> buf^1 (safe: buf^1's reads completed
// before tile t-1's boundary barrier), then issue ALL ds_reads + MFMAs of
// tile t with NO mid-tile barriers (compiler inserts counted lgkmcnt;
// LDS pipe overlaps MFMA pipe). Boundary: vmcnt(0) + s_barrier +
// sched_barrier(0). XOR swizzle byte^=(row&7)<<4 on ds_read; inverse
// pre-applied to the global staging source.
template <int EPI>
__global__ __launch_bounds__(512, 2) void gemm_bt3(
    const u16* __restrict__ A, const u16* __restrict__ B,
    int N, int K,
    u16* __restrict__ Cbf,
    const u16* __restrict__ U, int ldu,
    size_t sA, size_t sB, size_t sC, size_t sU) {
  __shared__ u16 lds[65536];  // 128 KiB
  const int tid = threadIdx.x;
  const int w = tid >> 6, l = tid & 63;
  const int wm2 = w >> 2, wn2 = w & 3;
  const int fr = l & 15, kg = l >> 4;

  const int bz = blockIdx.z;
  A += (size_t)bz * sA; B += (size_t)bz * sB; U += (size_t)bz * sU;

  // XCD-aware bijective swizzle (nwg % 8 == 0 for all launched shapes)
  const int nbx = gridDim.x;
  int li = blockIdx.y * nbx + blockIdx.x;
  const int cpx = (nbx * gridDim.y) >> 3;
  li = (li & 7) * cpx + (li >> 3);
  const int bn = li % nbx;
  const int bm = li / nbx;

  const int NT = K >> 6;                     // even for all callers
  const bool full = (bn * 256 + 256 <= N);   // block-uniform ragged flag

  const int r0 = (w << 3) + (l >> 3);                  // staging row 0..63
  const int cswz = (((l & 7) ^ (l >> 3)) & 7) << 3;    // inv-swizzled col

  // staging pointers: 4 panels x 2 row-groups; advance 128 elems / 2 tiles
  const u16* pA00 = A + (size_t)bm * 256 * K + (size_t)r0 * K + cswz;
  const u16* pA01 = pA00 + (size_t)64 * K;
  const u16* pA10 = pA00 + (size_t)128 * K;
  const u16* pA11 = pA00 + (size_t)192 * K;
  const u16* pB00 = B + (size_t)bn * 256 * K + (size_t)r0 * K + cswz;
  const u16* pB01 = pB00 + (size_t)64 * K;
  const u16* pB10 = pB00 + (size_t)128 * K;
  const u16* pB11 = pB00 + (size_t)192 * K;

  // precomputed swizzled LDS read bases
  const int X  = (l & 7) << 4;
  const int Y0 = (kg << 4) ^ X;
  const int Y1 = ((kg << 4) | 64) ^ X;
  const char* ldsC = (const char*)lds;
  const char* aR0 = ldsC + wm2 * 8192 + fr * 128 + Y0;
  const char* aR1 = ldsC + wm2 * 8192 + fr * 128 + Y1;
  const char* bR0 = ldsC + 32768 + wn2 * 4096 + fr * 128 + Y0;
  const char* bR1 = ldsC + 32768 + wn2 * 4096 + fr * 128 + Y1;

  // LDS stage destination: word off = buf*32768 + p*8192 + w*512 (+4096 L1)
  auto stg = [&](int bufw, int p, const u16* g0, const u16* g1, int ofs) {
    u16* d = lds + bufw * 32768 + p * 8192 + w * 512;
    gload16(g0 + ofs, d);
    gload16(g1 + ofs, d + 4096);
  };

  f32x4 acc[8][4];
#pragma unroll
  for (int i = 0; i < 8; i++)
#pragma unroll
    for (int j = 0; j < 4; j++) acc[i][j] = f32x4{0.f, 0.f, 0.f, 0.f};

  // prologue: stage tile 0 -> buf0; drain; barrier
  stg(0, 0, pA00, pA01, 0); stg(0, 2, pB00, pB01, 0);
  if (full) stg(0, 3, pB10, pB11, 0);
  stg(0, 1, pA10, pA11, 0);
  asm volatile("s_waitcnt vmcnt(0)" ::: "memory");
  __builtin_amdgcn_s_barrier();
  __builtin_amdgcn_sched_barrier(0);

  bf16x8 aH[4][2], bF[2][2][2];  // bF[qb][j][s]

#define MFMA_Q(QA, QB)                                                        \
  _Pragma("unroll") for (int s = 0; s < 2; s++)                               \
  _Pragma("unroll") for (int i = 0; i < 4; i++)                               \
  _Pragma("unroll") for (int j = 0; j < 2; j++)                               \
    acc[(QA)*4 + i][(QB)*2 + j] = __builtin_amdgcn_mfma_f32_16x16x32_bf16(    \
        aH[i][s], bF[QB][j][s], acc[(QA)*4 + i][(QB)*2 + j], 0, 0, 0);

#define TILE_STEP(BUF, ST, OFS)                                               \
  {                                                                           \
    /* stage tile t+1 -> other buffer (no ordering hazard) */                 \
    if (ST) {                                                                 \
      stg((BUF) ^ 1, 0, pA00, pA01, OFS);                                     \
      stg((BUF) ^ 1, 2, pB00, pB01, OFS);                                     \
      if (full) stg((BUF) ^ 1, 3, pB10, pB11, OFS);                           \
      stg((BUF) ^ 1, 1, pA10, pA11, OFS);                                     \
    }                                                                         \
    /* reads + MFMAs, compiler-scheduled (counted lgkmcnt auto-inserted) */   \
    _Pragma("unroll") for (int i = 0; i < 4; i++) {                           \
      aH[i][0] = *(const bf16x8*)(aR0 + (BUF) * 65536 + i * 2048);            \
      aH[i][1] = *(const bf16x8*)(aR1 + (BUF) * 65536 + i * 2048);            \
    }                                                                         \
    _Pragma("unroll") for (int j = 0; j < 2; j++) {                           \
      bF[0][j][0] = *(const bf16x8*)(bR0 + (BUF) * 65536 + j * 2048);         \
      bF[0][j][1] = *(const bf16x8*)(bR1 + (BUF) * 65536 + j * 2048);         \
    }                                                                         \
    MFMA_Q(0, 0)                                                              \
    if (full) {                                                               \
      _Pragma("unroll") for (int j = 0; j < 2; j++) {                         \
        bF[1][j][0] = *(const bf16x8*)(bR0 + (BUF) * 65536 + 16384 + j * 2048);\
        bF[1][j][1] = *(const bf16x8*)(bR1 + (BUF) * 65536 + 16384 + j * 2048);\
      }                                                                       \
      MFMA_Q(0, 1)                                                            \
    }                                                                         \
    _Pragma("unroll") for (int i = 0; i < 4; i++) {                           \
      aH[i][0] = *(const bf16x8*)(aR0 + (BUF) * 65536 + 16384 + i * 2048);    \
      aH[i][1] = *(const bf16x8*)(aR1 + (BUF) * 65536 + 16384 + i * 2048);    \
    }                                                                         \
    MFMA_Q(1, 0)                                                              \
    if (full) { MFMA_Q(1, 1) }                                                \
    /* boundary: own stages landed; all waves' reads done; pin order */       \
    asm volatile("s_waitcnt vmcnt(0)" ::: "memory");                          \
    __builtin_amdgcn_s_barrier();                                             \
    __builtin_amdgcn_sched_barrier(0);                                        \
  }

  for (int t2 = 0; t2 < NT; t2 += 2) {
    const bool st0 = (t2 + 1 < NT);
    const bool st1 = (t2 + 2 < NT);
    TILE_STEP(0, st0, 64)
    TILE_STEP(1, st1, 128)
    pA00 += 128; pA01 += 128; pA10 += 128; pA11 += 128;
    pB00 += 128; pB01 += 128; pB10 += 128; pB11 += 128;
  }
#undef TILE_STEP
#undef MFMA_Q

  // epilogue
  const int rsub = (l >> 4) * 4;
  const int ccol = l & 15;
#pragma unroll
  for (int ai = 0; ai < 8; ai++) {
#pragma unroll
    for (int bj = 0; bj < 4; bj++) {
      if (!full && bj >= 2) continue;
      int n = bn * 256 + (bj >> 1) * 128 + wn2 * 32 + (bj & 1) * 16 + ccol;
#pragma unroll
      for (int tt = 0; tt < 4; tt++) {
        int m = bm * 256 + (ai >> 2) * 128 + wm2 * 64 + (ai & 3) * 16 + rsub + tt;
        float v = acc[ai][bj][tt];
        size_t idx = (size_t)m * N + n;
        if constexpr (EPI == 0) {
          float sv = v / (1.f + __expf(-v));
          Cbf[(size_t)bz * sC + idx] = f2bf(sv);
        } else if constexpr (EPI == 1) {
          float sc = v * 0.08838834764831845f;  // 1/sqrt(128)
          sc = sc > 0.f ? sc * sc : 0.f;
          Cbf[(size_t)bz * sC + idx] = f2bf(sc);
        } else {
          float uvl = bf2f(U[(size_t)m * ldu + n]);
          Cbf[(size_t)bz * sC + idx] = f2bf(v * uvl);
        }
      }
    }
  }
}

// ======== 256x128 deep-pipeline GEMM (gemm3; round-3 proven) ====
template <int EPI>
__global__ __launch_bounds__(512, 2) void gemm_bt2(
    const u16* __restrict__ A, const u16* __restrict__ B,
    int M, int N, int K,
    u16* __restrict__ Cbf, float* __restrict__ Cf,
    const u16* __restrict__ U, int ldu,
    const float* __restrict__ Xres, const float* __restrict__ rscale,
    size_t sA, size_t sB, size_t sC, size_t sU) {
  __shared__ u16 lds[3 * 24576];  // 144 KiB
  const int tid = threadIdx.x;
  const int w = tid >> 6, l = tid & 63;
  const int wr = w >> 1, wc = w & 1;
  const int fr = l & 15, kg = l >> 4;

  const int bz = blockIdx.z;
  A += (size_t)bz * sA; B += (size_t)bz * sB; U += (size_t)bz * sU;

  const int nbx = gridDim.x;
  int li = blockIdx.y * nbx + blockIdx.x;
  const int cpx = (nbx * gridDim.y) >> 3;
  li = (li & 7) * cpx + (li >> 3);
  const int bn = li % nbx;
  const int bm = li / nbx;

  const int NT = K >> 6;
  const int srow = (w << 3) + (l >> 3);
  const int scol = (((l & 7) ^ (l >> 3)) & 7) << 3;
  const size_t aoff = (size_t)bm * 256 * K;
  const size_t boff = (size_t)bn * 128 * K;
  const char* ldsC = (const char*)lds;

  auto stageAu = [&](int t, int h) {
    int sb = (t % 3) * 24576 + h * 8192;
    const u16* g = A + aoff + (size_t)(h * 128 + srow) * K + t * 64 + scol;
#pragma unroll
    for (int L = 0; L < 2; L++)
      gload16(g + (size_t)(L * 64) * K, &lds[sb + (L * 8 + w) * 512]);
  };
  auto stageBu = [&](int t) {
    int sb = (t % 3) * 24576 + 16384;
    const u16* g = B + boff + (size_t)srow * K + t * 64 + scol;
#pragma unroll
    for (int L = 0; L < 2; L++)
      gload16(g + (size_t)(L * 64) * K, &lds[sb + (L * 8 + w) * 512]);
  };
  auto ldA = [&](int cur, int i, int s) -> bf16x8 {
    int r = ((wr & 1) << 6) + (i << 4) + fr;
    int off = cur * 49152 + ((wr >> 1) << 14) + (r << 7) + (s << 6) + (kg << 4);
    off ^= (r & 7) << 4;
    return *(const bf16x8*)(ldsC + off);
  };
  auto ldB = [&](int cur, int j, int s) -> bf16x8 {
    int r = (wc << 6) + (j << 4) + fr;
    int off = cur * 49152 + 32768 + (r << 7) + (s << 6) + (kg << 4);
    off ^= (r & 7) << 4;
    return *(const bf16x8*)(ldsC + off);
  };

  f32x4 acc[4][4];
#pragma unroll
  for (int i = 0; i < 4; i++)
#pragma unroll
    for (int j = 0; j < 4; j++) acc[i][j] = f32x4{0.f, 0.f, 0.f, 0.f};

  stageAu(0, 0); stageAu(0, 1); stageBu(0);
  if (NT > 1) { stageAu(1, 0); stageAu(1, 1); stageBu(1); }
  asm volatile("s_waitcnt vmcnt(6)" ::: "memory");
  __builtin_amdgcn_s_barrier();

  bf16x8 aF[2][2], bF[2][2][2];
  for (int t = 0; t < NT; ++t) {
    const int cur = t % 3;
    const bool st = (t + 2 < NT);
#pragma unroll
    for (int i = 0; i < 2; i++)
#pragma unroll
      for (int s = 0; s < 2; s++) aF[i][s] = ldA(cur, i, s);
#pragma unroll
    for (int j = 0; j < 2; j++)
#pragma unroll
      for (int s = 0; s < 2; s++) bF[0][j][s] = ldB(cur, j, s);
    if (st) stageAu(t + 2, 0);
    __builtin_amdgcn_s_barrier();
    __builtin_amdgcn_s_setprio(1);
#pragma unroll
    for (int s = 0; s < 2; s++)
#pragma unroll
      for (int i = 0; i < 2; i++)
#pragma unroll
        for (int j = 0; j < 2; j++)
          acc[i][j] = __builtin_amdgcn_mfma_f32_16x16x32_bf16(aF[i][s], bF[0][j][s], acc[i][j], 0, 0, 0);
    __builtin_amdgcn_s_setprio(0);
    __builtin_amdgcn_s_barrier();
#pragma unroll
    for (int j = 0; j < 2; j++)
#pragma unroll
      for (int s = 0; s < 2; s++) bF[1][j][s] = ldB(cur, 2 + j, s);
    if (st) stageAu(t + 2, 1);
    __builtin_amdgcn_s_barrier();
    __builtin_amdgcn_s_setprio(1);
#pragma unroll
    for (int s = 0; s < 2; s++)
#pragma unroll
      for (int i = 0; i < 2; i++)
#pragma unroll
        for (int j = 0; j < 2; j++)
          acc[i][2 + j] = __builtin_amdgcn_mfma_f32_16x16x32_bf16(aF[i][s], bF[1][j][s], acc[i][2 + j], 0, 0, 0);
    __builtin_amdgcn_s_setprio(0);
    __builtin_amdgcn_s_barrier();
#pragma unroll
    for (int i = 0; i < 2; i++)
#pragma unroll
      for (int s = 0; s < 2; s++) aF[i][s] = ldA(cur, 2 + i, s);
    if (st) stageBu(t + 2);
    __builtin_amdgcn_s_barrier();
    __builtin_amdgcn_s_setprio(1);
#pragma unroll
    for (int s = 0; s < 2; s++)
#pragma unroll
      for (int i = 0; i < 2; i++)
#pragma unroll
        for (int j = 0; j < 2; j++)
          acc[2 + i][j] = __builtin_amdgcn_mfma_f32_16x16x32_bf16(aF[i][s], bF[0][j][s], acc[2 + i][j], 0, 0, 0);
    __builtin_amdgcn_s_setprio(0);
    __builtin_amdgcn_s_barrier();
    __builtin_amdgcn_s_setprio(1);
#pragma unroll
    for (int s = 0; s < 2; s++)
#pragma unroll
      for (int i = 0; i < 2; i++)
#pragma unroll
        for (int j = 0; j < 2; j++)
          acc[2 + i][2 + j] = __builtin_amdgcn_mfma_f32_16x16x32_bf16(aF[i][s], bF[1][j][s], acc[2 + i][2 + j], 0, 0, 0);
    __builtin_amdgcn_s_setprio(0);
    if (st) asm volatile("s_waitcnt vmcnt(6)" ::: "memory");
    else    asm volatile("s_waitcnt vmcnt(0)" ::: "memory");
    __builtin_amdgcn_s_barrier();
  }

  const int m0 = bm * 256 + wr * 64;
  const int n0 = bn * 128 + wc * 64;
  const int rsub = (l >> 4) * 4;
  const int ccol = l & 15;
#pragma unroll
  for (int i = 0; i < 4; i++) {
#pragma unroll
    for (int j = 0; j < 4; j++) {
      int n = n0 + j * 16 + ccol;
#pragma unroll
      for (int tt = 0; tt < 4; tt++) {
        int m = m0 + i * 16 + rsub + tt;
        float v = acc[i][j][tt];
        size_t idx = (size_t)m * N + n;
        if constexpr (EPI == 0) {
          float sv = v / (1.f + __expf(-v));
          Cbf[(size_t)bz * sC + idx] = f2bf(sv);
        } else if constexpr (EPI == 1) {
          float sc = v * 0.08838834764831845f;
          sc = sc > 0.f ? sc * sc : 0.f;
          Cbf[(size_t)bz * sC + idx] = f2bf(sc);
        } else if constexpr (EPI == 2) {
          float uvl = bf2f(U[(size_t)m * ldu + n]);
          Cbf[(size_t)bz * sC + idx] = f2bf(v * uvl);
        } else {
          Cf[idx] = Xres[idx] * rscale[n] + v;
        }
      }
    }
  }
}

// ---------------- legacy 128x128 GEMM (fallback path only) ----------------
template <int EPI>
__global__ __launch_bounds__(256) void gemm_bt(
    const u16* __restrict__ A, const u16* __restrict__ B,
    int M, int N, int K,
    u16* __restrict__ Cbf, float* __restrict__ Cf,
    const u16* __restrict__ U, int ldu,
    const float* __restrict__ Xres, const float* __restrict__ rscale,
    size_t sA, size_t sB, size_t sC, size_t sU) {
  __shared__ u16 As[128 * 32];
  __shared__ u16 Bs[128 * 32];
  const int tid = threadIdx.x;
  const int wave = tid >> 6, lane = tid & 63;
  const int wr = wave >> 1, wc = wave & 1;
  const int bz = blockIdx.z;
  A += (size_t)bz * sA; B += (size_t)bz * sB; U += (size_t)bz * sU;
  const int nbx = gridDim.x;
  int li = blockIdx.y * nbx + blockIdx.x;
  const int cpx = (nbx * gridDim.y) >> 3;
  li = (li & 7) * cpx + (li >> 3);
  const int bn = li % nbx;
  const int bm = li / nbx;
  const size_t abase = (size_t)bm * 128 * K;
  const size_t bbase = (size_t)bn * 128 * K;
  const int srow = tid >> 2;
  const int scol = (tid & 3) * 8;
  f32x4 acc[4][4];
#pragma unroll
  for (int i = 0; i < 4; i++)
#pragma unroll
    for (int j = 0; j < 4; j++) acc[i][j] = f32x4{0.f, 0.f, 0.f, 0.f};
  const int fr = lane & 15;
  const int fk = (lane >> 4) * 8;
  for (int k0 = 0; k0 < K; k0 += 32) {
#pragma unroll
    for (int r = 0; r < 2; r++) {
      const u16* gA = A + abase + (size_t)(r * 64 + srow) * K + k0 + scol;
      const u16* gB = B + bbase + (size_t)(r * 64 + srow) * K + k0 + scol;
      gload16(gA, As + r * 2048 + wave * 512);
      gload16(gB, Bs + r * 2048 + wave * 512);
    }
    __syncthreads();
    bf16x8 af[4], bfr[4];
#pragma unroll
    for (int i = 0; i < 4; i++) {
      af[i]  = *reinterpret_cast<const bf16x8*>(&As[(wr * 64 + i * 16 + fr) * 32 + fk]);
      bfr[i] = *reinterpret_cast<const bf16x8*>(&Bs[(wc * 64 + i * 16 + fr) * 32 + fk]);
    }
#pragma unroll
    for (int i = 0; i < 4; i++)
#pragma unroll
      for (int j = 0; j < 4; j++)
        acc[i][j] = __builtin_amdgcn_mfma_f32_16x16x32_bf16(af[i], bfr[j], acc[i][j], 0, 0, 0);
    __syncthreads();
  }
  const int m0 = bm * 128 + wr * 64;
  const int n0 = bn * 128 + wc * 64;
  const int rsub = (lane >> 4) * 4;
  const int ccol = lane & 15;
#pragma unroll
  for (int i = 0; i < 4; i++) {
#pragma unroll
    for (int j = 0; j < 4; j++) {
      int n = n0 + j * 16 + ccol;
#pragma unroll
      for (int t = 0; t < 4; t++) {
        int m = m0 + i * 16 + rsub + t;
        float v = acc[i][j][t];
        size_t idx = (size_t)m * N + n;
        if constexpr (EPI == 0) {
          float sv = v / (1.f + __expf(-v));
          Cbf[(size_t)bz * sC + idx] = f2bf(sv);
        } else if constexpr (EPI == 1) {
          float sc = v * 0.08838834764831845f;
          sc = sc > 0.f ? sc * sc : 0.f;
          Cbf[(size_t)bz * sC + idx] = f2bf(sc);
        } else if constexpr (EPI == 2) {
          float uvl = bf2f(U[(size_t)m * ldu + n]);
          Cbf[(size_t)bz * sC + idx] = f2bf(v * uvl);
        } else {
          Cf[idx] = Xres[idx] * rscale[n] + v;
        }
      }
    }
  }
}

// ---------------- launcher ----------------

extern "C" void kernel_launch(void* const* d_in, const int* in_sizes, int n_in,
                              void* d_out, int out_size, void* d_ws, size_t ws_size,
                              hipStream_t stream) {
  const float* x        = (const float*)d_in[0];
  const float* pos_enc  = (const float*)d_in[1];
  const float* uv_w     = (const float*)d_in[2];
  const float* o_w      = (const float*)d_in[3];
  const float* gamma    = (const float*)d_in[4];
  const float* beta     = (const float*)d_in[5];
  const float* ln_g     = (const float*)d_in[6];
  const float* res_scale= (const float*)d_in[7];
  float* out = (float*)d_out;

  auto al = [](size_t b) { return (b + 255) & ~(size_t)255; };
  const size_t SZ_UVW  = (size_t)FDIM * DDIM * 2;
  const size_t SZ_OW   = (size_t)DDIM * EDIM * 2;
  const size_t SZ_Z    = (size_t)NBATCH * SEQ * EDIM * 2;
  const size_t SZ_XN   = (size_t)NBATCH * SEQ * DDIM * 2;
  const size_t SZ_UV   = (size_t)NBATCH * SEQ * FDIM * 2;
  const size_t SZ_QK   = (size_t)NBATCH * SEQ * SATT * 2;
  const size_t SZ_VT1  = (size_t)EDIM * SEQ * 2;
  const size_t SZ_P1   = (size_t)SEQ * SEQ * 2;
  const size_t need_full =
      al(SZ_UVW) + al(SZ_OW) + al(SZ_Z) + al(SZ_XN) + al(SZ_UV) + 2 * al(SZ_QK) +
      (size_t)NBATCH * (al(SZ_VT1) + al(SZ_P1));
  const bool FULL = ws_size >= need_full;

  char* p = (char*)d_ws;
  auto alloc = [&](size_t bytes) {
    char* r = p;
    p += (bytes + 255) & ~(size_t)255;
    return r;
  };

  if (FULL) {
    u16* uvw_bf = (u16*)alloc(SZ_UVW);
    u16* ow_bf  = (u16*)alloc(SZ_OW);
    u16* z      = (u16*)alloc(SZ_Z);
    u16* vt     = (u16*)alloc((size_t)NBATCH * al(SZ_VT1));
    u16* pmat   = (u16*)alloc((size_t)NBATCH * al(SZ_P1));
    u16* xn     = (u16*)alloc(SZ_XN);
    u16* uv     = (u16*)alloc(SZ_UV);
    u16* qb     = (u16*)alloc(SZ_QK);
    u16* kb     = (u16*)alloc(SZ_QK);
    const size_t sVT = al(SZ_VT1) >> 1;
    const size_t sP  = al(SZ_P1) >> 1;
    const int rows = NBATCH * SEQ;  // 8192

    cvt_bf16_kernel<<<(FDIM * DDIM / 4 + 255) / 256, 256, 0, stream>>>(
        uv_w, uvw_bf, FDIM * DDIM / 4);
    cvt_bf16_kernel<<<(DDIM * EDIM / 4 + 255) / 256, 256, 0, stream>>>(
        o_w, ow_bf, DDIM * EDIM / 4);

    rms_kernel<<<rows, 256, 0, stream>>>(x, ln_g, xn);
    // gemm0: 17 col-tiles, last one ragged (128 wide) -> 544 blocks, 512 full
    gemm_bt3<0><<<dim3(17, rows / 256), 512, 0, stream>>>(
        xn, uvw_bf, FDIM, DDIM, uv, nullptr, 0, 0, 0, 0, 0);
    qk_kernel<<<rows, SATT, 0, stream>>>(uv, pos_enc, gamma, beta, qb, kb, FDIM);
    transpose_v<<<dim3(EDIM / 32, SEQ / 32, NBATCH), dim3(32, 8), 0, stream>>>(uv, vt, FDIM);
    gemm_bt3<1><<<dim3(SEQ / 256, SEQ / 256, NBATCH), 512, 0, stream>>>(
        qb, kb, SEQ, SATT, pmat, nullptr, 0,
        (size_t)SEQ * SATT, (size_t)SEQ * SATT, sP, 0);
    gemm_bt3<2><<<dim3(EDIM / 256, SEQ / 256, NBATCH), 512, 0, stream>>>(
        pmat, vt, EDIM, SEQ, z, uv, FDIM,
        sP, sVT, (size_t)SEQ * EDIM, (size_t)SEQ * FDIM);
    gemm_bt2<3><<<dim3(DDIM / 128, rows / 256), 512, 0, stream>>>(
        z, ow_bf, rows, DDIM, EDIM, nullptr, out, nullptr, 0,
        x, res_scale, 0, 0, 0, 0);
    return;
  }

  // ---------- fallback (small workspace): round-2 structure ----------
  u16* uvw_bf = (u16*)alloc(SZ_UVW);
  u16* ow_bf  = (u16*)alloc(SZ_OW);
  u16* z      = (u16*)alloc(SZ_Z);
  u16* vt     = (u16*)alloc(SZ_VT1);
  u16* pmat   = (u16*)alloc(SZ_P1);
  size_t fixed = (size_t)(p - (char*)d_ws);
  const size_t perbc = (size_t)SEQ * DDIM * 2 + (size_t)SEQ * FDIM * 2 +
                       2 * (size_t)SEQ * SATT * 2 + 4 * 256;
  int BC = (ws_size >= fixed + 4 * perbc) ? 4 : 1;
  u16* xn = (u16*)alloc((size_t)BC * SEQ * DDIM * 2);
  u16* uv = (u16*)alloc((size_t)BC * SEQ * FDIM * 2);
  u16* qb = (u16*)alloc((size_t)BC * SEQ * SATT * 2);
  u16* kb = (u16*)alloc((size_t)BC * SEQ * SATT * 2);

  cvt_bf16_kernel<<<(FDIM * DDIM / 4 + 255) / 256, 256, 0, stream>>>(
      uv_w, uvw_bf, FDIM * DDIM / 4);
  cvt_bf16_kernel<<<(DDIM * EDIM / 4 + 255) / 256, 256, 0, stream>>>(
      o_w, ow_bf, DDIM * EDIM / 4);

  for (int b0 = 0; b0 < NBATCH; b0 += BC) {
    int rows = BC * SEQ;
    rms_kernel<<<rows, 256, 0, stream>>>(x + (size_t)b0 * SEQ * DDIM, ln_g, xn);
    gemm_bt<0><<<dim3(FDIM / 128, rows / 128), 256, 0, stream>>>(
        xn, uvw_bf, rows, FDIM, DDIM, uv, nullptr, nullptr, 0, nullptr, nullptr,
        0, 0, 0, 0);
    qk_kernel<<<rows, SATT, 0, stream>>>(uv, pos_enc, gamma, beta, qb, kb, FDIM);
    for (int bb = 0; bb < BC; bb++) {
      int b = b0 + bb;
      const u16* uvb = uv + (size_t)bb * SEQ * FDIM;
      transpose_v<<<dim3(EDIM / 32, SEQ / 32, 1), dim3(32, 8), 0, stream>>>(uvb, vt, FDIM);
      gemm_bt<1><<<dim3(SEQ / 128, SEQ / 128), 256, 0, stream>>>(
          qb + (size_t)bb * SEQ * SATT, kb + (size_t)bb * SEQ * SATT,
          SEQ, SEQ, SATT, pmat, nullptr, nullptr, 0, nullptr, nullptr,
          0, 0, 0, 0);
      gemm_bt<2><<<dim3(EDIM / 128, SEQ / 128), 256, 0, stream>>>(
          pmat, vt, SEQ, EDIM, SEQ, z + (size_t)b * SEQ * EDIM, nullptr,
          uvb, FDIM, nullptr, nullptr, 0, 0, 0, 0);
    }
  }
  gemm_bt<3><<<dim3(DDIM / 128, (NBATCH * SEQ) / 128), 256, 0, stream>>>(
      z, ow_bf, NBATCH * SEQ, DDIM, EDIM, nullptr, out, nullptr, 0,
      x, res_scale, 0, 0, 0, 0);
}